// Round 1
// baseline (7412.273 us; speedup 1.0000x reference)
//
#include <hip/hip_runtime.h>

#define THREADS 256

// ---------------- degree kernels ----------------
__global__ __launch_bounds__(THREADS) void k_deg_init(float* deg, int n) {
    int i = blockIdx.x * THREADS + threadIdx.x;
    if (i < n) deg[i] = 1.0f;
}

__global__ __launch_bounds__(THREADS) void k_deg_accum(const int* __restrict__ dst,
                                                       float* __restrict__ deg, int E) {
    int e = blockIdx.x * THREADS + threadIdx.x;
    if (e < E) atomicAdd(&deg[dst[e]], 1.0f);
}

// deg -> deg^{-1/2} in place
__global__ __launch_bounds__(THREADS) void k_deg_xform(float* deg, int n) {
    int i = blockIdx.x * THREADS + threadIdx.x;
    if (i < n) deg[i] = rsqrtf(deg[i]);
}

// ---------------- GEMM: C[M][128] = A[M][128] @ B[128][128] ----------------
// block: 256 threads, BM=64, full N=128, BK=32
__global__ __launch_bounds__(THREADS) void k_gemm128(const float* __restrict__ A,
                                                     const float* __restrict__ B,
                                                     float* __restrict__ C, int M) {
    __shared__ float4 As[64][8];   // 64 rows x 32 k (as 8 float4)  = 8 KB
    __shared__ float4 Bs[32][32];  // 32 k x 128 cols (as 32 float4) = 16 KB

    int tid = threadIdx.x;
    int tx = tid & 31;        // col quad: cols tx*4..tx*4+3
    int ty = tid >> 5;        // row group: rows ty*8..ty*8+7
    int row0 = blockIdx.x * 64;

    float4 acc[8];
#pragma unroll
    for (int i = 0; i < 8; i++) acc[i] = make_float4(0.f, 0.f, 0.f, 0.f);

    for (int k0 = 0; k0 < 128; k0 += 32) {
        // stage A tile (guard M tail)
#pragma unroll
        for (int i = 0; i < 2; i++) {
            int idx = tid + i * 256;          // 0..511
            int r = idx >> 3, q = idx & 7;
            int row = row0 + r;
            float4 v = make_float4(0.f, 0.f, 0.f, 0.f);
            if (row < M) v = *(const float4*)(A + (size_t)row * 128 + k0 + q * 4);
            As[r][q] = v;
        }
        // stage B tile
#pragma unroll
        for (int i = 0; i < 4; i++) {
            int idx = tid + i * 256;          // 0..1023
            int r = idx >> 5, c4 = idx & 31;
            Bs[r][c4] = *(const float4*)(B + (size_t)(k0 + r) * 128 + c4 * 4);
        }
        __syncthreads();

#pragma unroll
        for (int k4 = 0; k4 < 8; k4++) {
            float4 b0 = Bs[k4 * 4 + 0][tx];
            float4 b1 = Bs[k4 * 4 + 1][tx];
            float4 b2 = Bs[k4 * 4 + 2][tx];
            float4 b3 = Bs[k4 * 4 + 3][tx];
#pragma unroll
            for (int i = 0; i < 8; i++) {
                float4 a = As[ty * 8 + i][k4];
                acc[i].x = fmaf(a.x, b0.x, fmaf(a.y, b1.x, fmaf(a.z, b2.x, fmaf(a.w, b3.x, acc[i].x))));
                acc[i].y = fmaf(a.x, b0.y, fmaf(a.y, b1.y, fmaf(a.z, b2.y, fmaf(a.w, b3.y, acc[i].y))));
                acc[i].z = fmaf(a.x, b0.z, fmaf(a.y, b1.z, fmaf(a.z, b2.z, fmaf(a.w, b3.z, acc[i].z))));
                acc[i].w = fmaf(a.x, b0.w, fmaf(a.y, b1.w, fmaf(a.z, b2.w, fmaf(a.w, b3.w, acc[i].w))));
            }
        }
        __syncthreads();
    }

#pragma unroll
    for (int i = 0; i < 8; i++) {
        int row = row0 + ty * 8 + i;
        if (row < M) *(float4*)(C + (size_t)row * 128 + tx * 4) = acc[i];
    }
}

// ---------------- scatter aggregate ----------------
// thread handles (edge, 4 channels): agg[dst] += xw[src] * dinv[src]*dinv[dst]
__global__ __launch_bounds__(THREADS) void k_aggregate(const int* __restrict__ src,
                                                       const int* __restrict__ dst,
                                                       const float* __restrict__ xw,
                                                       const float* __restrict__ dinv,
                                                       float* __restrict__ agg, int E) {
    int tid = blockIdx.x * THREADS + threadIdx.x;
    int e = tid >> 5;
    int c4 = tid & 31;
    if (e >= E) return;
    int s = src[e], d = dst[e];
    float nrm = dinv[s] * dinv[d];
    float4 v = *(const float4*)(xw + (size_t)s * 128 + c4 * 4);
    float* p = agg + (size_t)d * 128 + c4 * 4;
    atomicAdd(p + 0, v.x * nrm);
    atomicAdd(p + 1, v.y * nrm);
    atomicAdd(p + 2, v.z * nrm);
    atomicAdd(p + 3, v.w * nrm);
}

// ---------------- finalize: h = relu(agg + xw/deg + b) (in-place on agg) ----------------
__global__ __launch_bounds__(THREADS) void k_finalize(const float* __restrict__ agg,
                                                      const float* __restrict__ xw,
                                                      const float* __restrict__ dinv,
                                                      const float* __restrict__ bias,
                                                      float* __restrict__ h, int n) {
    int tid = blockIdx.x * THREADS + threadIdx.x;
    int node = tid >> 5, c4 = tid & 31;
    if (node >= n) return;
    float di = dinv[node];
    float invdeg = di * di;   // 1/deg
    float4 a = *(const float4*)(agg + (size_t)node * 128 + c4 * 4);
    float4 x = *(const float4*)(xw + (size_t)node * 128 + c4 * 4);
    float4 b = *(const float4*)(bias + c4 * 4);
    float4 r;
    r.x = fmaxf(fmaf(x.x, invdeg, a.x) + b.x, 0.f);
    r.y = fmaxf(fmaf(x.y, invdeg, a.y) + b.y, 0.f);
    r.z = fmaxf(fmaf(x.z, invdeg, a.z) + b.z, 0.f);
    r.w = fmaxf(fmaf(x.w, invdeg, a.w) + b.w, 0.f);
    *(float4*)(h + (size_t)node * 128 + c4 * 4) = r;
}

// ---------------- edge head ----------------
// 32 edges / block. ef = [x*y, x-y] staged in LDS (32x256 f32 = 32 KB).
// 256 thr: tx=col quad (128 cols), ty=edge group (4 edges each). acc[4] float4.
__global__ __launch_bounds__(THREADS) void k_edge_head(const int* __restrict__ src,
                                                       const int* __restrict__ dst,
                                                       const float* __restrict__ h,
                                                       const float* __restrict__ fc1w,
                                                       const float* __restrict__ fc1b,
                                                       const float* __restrict__ fc2w,
                                                       const float* __restrict__ fc2b,
                                                       float* __restrict__ out, int E) {
    __shared__ float4 ef[32][64];   // [edge][k quad], k = 0..255
    int tid = threadIdx.x;
    int e0 = blockIdx.x * 32;

#pragma unroll
    for (int i = 0; i < 4; i++) {
        int idx = tid + i * 256;          // 0..1023
        int e = idx >> 5, c4 = idx & 31;
        int ee = e0 + e;
        float4 p = make_float4(0.f, 0.f, 0.f, 0.f);
        float4 dq = p;
        if (ee < E) {
            int s = src[ee], d = dst[ee];
            float4 xv = *(const float4*)(h + (size_t)s * 128 + c4 * 4);
            float4 yv = *(const float4*)(h + (size_t)d * 128 + c4 * 4);
            p  = make_float4(xv.x * yv.x, xv.y * yv.y, xv.z * yv.z, xv.w * yv.w);
            dq = make_float4(xv.x - yv.x, xv.y - yv.y, xv.z - yv.z, xv.w - yv.w);
        }
        ef[e][c4] = p;
        ef[e][32 + c4] = dq;
    }
    __syncthreads();

    int tx = tid & 31;   // cols tx*4..+3
    int ty = tid >> 5;   // edges ty*4..+3
    float4 acc[4];
#pragma unroll
    for (int i = 0; i < 4; i++) acc[i] = make_float4(0.f, 0.f, 0.f, 0.f);

#pragma unroll 2
    for (int k4 = 0; k4 < 64; k4++) {
        float4 w0 = *(const float4*)(fc1w + (size_t)(k4 * 4 + 0) * 128 + tx * 4);
        float4 w1 = *(const float4*)(fc1w + (size_t)(k4 * 4 + 1) * 128 + tx * 4);
        float4 w2 = *(const float4*)(fc1w + (size_t)(k4 * 4 + 2) * 128 + tx * 4);
        float4 w3 = *(const float4*)(fc1w + (size_t)(k4 * 4 + 3) * 128 + tx * 4);
#pragma unroll
        for (int i = 0; i < 4; i++) {
            float4 a = ef[ty * 4 + i][k4];
            acc[i].x = fmaf(a.x, w0.x, fmaf(a.y, w1.x, fmaf(a.z, w2.x, fmaf(a.w, w3.x, acc[i].x))));
            acc[i].y = fmaf(a.x, w0.y, fmaf(a.y, w1.y, fmaf(a.z, w2.y, fmaf(a.w, w3.y, acc[i].y))));
            acc[i].z = fmaf(a.x, w0.z, fmaf(a.y, w1.z, fmaf(a.z, w2.z, fmaf(a.w, w3.z, acc[i].z))));
            acc[i].w = fmaf(a.x, w0.w, fmaf(a.y, w1.w, fmaf(a.z, w2.w, fmaf(a.w, w3.w, acc[i].w))));
        }
    }

    float4 b1 = *(const float4*)(fc1b + tx * 4);
    float4 wv = *(const float4*)(fc2w + tx * 4);
    float bias2 = fc2b[0];

#pragma unroll
    for (int i = 0; i < 4; i++) {
        float zx = fmaxf(acc[i].x + b1.x, 0.f);
        float zy = fmaxf(acc[i].y + b1.y, 0.f);
        float zz = fmaxf(acc[i].z + b1.z, 0.f);
        float zw = fmaxf(acc[i].w + b1.w, 0.f);
        float part = zx * wv.x + zy * wv.y + zz * wv.z + zw * wv.w;
#pragma unroll
        for (int m = 16; m > 0; m >>= 1) part += __shfl_xor(part, m);
        if (tx == 0) {
            int ee = e0 + ty * 4 + i;
            if (ee < E) out[ee] = 1.0f / (1.0f + expf(-(part + bias2)));
        }
    }
}

// ---------------- host ----------------
extern "C" void kernel_launch(void* const* d_in, const int* in_sizes, int n_in,
                              void* d_out, int out_size, void* d_ws, size_t ws_size,
                              hipStream_t stream) {
    const float* x    = (const float*)d_in[0];
    const int*   ei   = (const int*)d_in[1];
    const float* W1   = (const float*)d_in[2];
    const float* b1   = (const float*)d_in[3];
    const float* W2   = (const float*)d_in[4];
    const float* b2   = (const float*)d_in[5];
    const float* fc1w = (const float*)d_in[6];
    const float* fc1b = (const float*)d_in[7];
    const float* fc2w = (const float*)d_in[8];
    const float* fc2b = (const float*)d_in[9];

    int N = in_sizes[0] / 128;
    int E = in_sizes[1] / 2;
    const int* src = ei;
    const int* dst = ei + E;

    char* ws = (char*)d_ws;
    size_t szDinv = ((size_t)N * 4 + 255) & ~(size_t)255;
    size_t szMat  = ((size_t)N * 128 * 4 + 255) & ~(size_t)255;
    float* dinv = (float*)ws;
    float* xw   = (float*)(ws + szDinv);
    float* agg  = (float*)(ws + szDinv + szMat);   // also holds h1 / h2 after finalize

    int gN   = (N + THREADS - 1) / THREADS;
    int gE   = (E + THREADS - 1) / THREADS;
    int gMat = (int)(((size_t)N * 32 + THREADS - 1) / THREADS);
    int gAgg = (int)(((size_t)E * 32 + THREADS - 1) / THREADS);
    int gGemm = (N + 63) / 64;
    int gHead = (E + 31) / 32;

    // degrees -> dinv
    k_deg_init<<<gN, THREADS, 0, stream>>>(dinv, N);
    k_deg_accum<<<gE, THREADS, 0, stream>>>(dst, dinv, E);
    k_deg_xform<<<gN, THREADS, 0, stream>>>(dinv, N);

    // ---- layer 1 ----
    k_gemm128<<<gGemm, THREADS, 0, stream>>>(x, W1, xw, N);
    hipMemsetAsync(agg, 0, (size_t)N * 128 * 4, stream);
    k_aggregate<<<gAgg, THREADS, 0, stream>>>(src, dst, xw, dinv, agg, E);
    k_finalize<<<gMat, THREADS, 0, stream>>>(agg, xw, dinv, b1, agg, N);   // h1 in agg

    // ---- layer 2 ----
    k_gemm128<<<gGemm, THREADS, 0, stream>>>(agg, W2, xw, N);              // xw2 = h1 @ W2
    hipMemsetAsync(agg, 0, (size_t)N * 128 * 4, stream);
    k_aggregate<<<gAgg, THREADS, 0, stream>>>(src, dst, xw, dinv, agg, E);
    k_finalize<<<gMat, THREADS, 0, stream>>>(agg, xw, dinv, b2, agg, N);   // h2 in agg

    // ---- edge head ----
    k_edge_head<<<gHead, THREADS, 0, stream>>>(src, dst, agg, fc1w, fc1b, fc2w, fc2b,
                                               (float*)d_out, E);
}

// Round 2
// 2050.957 us; speedup vs baseline: 3.6141x; 3.6141x over previous
//
#include <hip/hip_runtime.h>

#define THREADS 256

// ================= CSR build: histogram -> scan -> scatter =================

__global__ __launch_bounds__(THREADS) void k_hist(const int* __restrict__ dst,
                                                  int* __restrict__ cnt, int E) {
    int e = blockIdx.x * THREADS + threadIdx.x;
    if (e < E) atomicAdd(&cnt[dst[e]], 1);
}

// dinv[i] = rsqrt(cnt[i] + 1)
__global__ __launch_bounds__(THREADS) void k_dinv(const int* __restrict__ cnt,
                                                  float* __restrict__ dinv, int n) {
    int i = blockIdx.x * THREADS + threadIdx.x;
    if (i < n) dinv[i] = rsqrtf((float)cnt[i] + 1.0f);
}

// chunk = 1024 elements per block (256 thr x 4). exclusive scan within chunk.
__global__ __launch_bounds__(THREADS) void k_scan1(const int* __restrict__ cnt,
                                                   int* __restrict__ rowptr,
                                                   int* __restrict__ blockSums, int n) {
    __shared__ int part[THREADS];
    int tid = threadIdx.x;
    int base = blockIdx.x * 1024 + tid * 4;
    int v0 = (base + 0 < n) ? cnt[base + 0] : 0;
    int v1 = (base + 1 < n) ? cnt[base + 1] : 0;
    int v2 = (base + 2 < n) ? cnt[base + 2] : 0;
    int v3 = (base + 3 < n) ? cnt[base + 3] : 0;
    part[tid] = v0 + v1 + v2 + v3;
    __syncthreads();
    for (int off = 1; off < THREADS; off <<= 1) {
        int t = 0;
        if (tid >= off) t = part[tid - off];
        __syncthreads();
        if (tid >= off) part[tid] += t;
        __syncthreads();
    }
    int excl = (tid == 0) ? 0 : part[tid - 1];
    if (tid == THREADS - 1) blockSums[blockIdx.x] = part[THREADS - 1];
    int run = excl;
    if (base + 0 < n) rowptr[base + 0] = run; run += v0;
    if (base + 1 < n) rowptr[base + 1] = run; run += v1;
    if (base + 2 < n) rowptr[base + 2] = run; run += v2;
    if (base + 3 < n) rowptr[base + 3] = run;
}

// single block: exclusive-scan blockSums (nchunks <= 256); also rowptr[n] = E
__global__ __launch_bounds__(THREADS) void k_scan2(int* __restrict__ blockSums,
                                                   int* __restrict__ rowptr,
                                                   int nchunks, int n, int E) {
    __shared__ int part[THREADS];
    int tid = threadIdx.x;
    int v = (tid < nchunks) ? blockSums[tid] : 0;
    part[tid] = v;
    __syncthreads();
    for (int off = 1; off < THREADS; off <<= 1) {
        int t = 0;
        if (tid >= off) t = part[tid - off];
        __syncthreads();
        if (tid >= off) part[tid] += t;
        __syncthreads();
    }
    int excl = (tid == 0) ? 0 : part[tid - 1];
    if (tid < nchunks) blockSums[tid] = excl;
    if (tid == 0) rowptr[n] = E;
}

__global__ __launch_bounds__(THREADS) void k_scan3(int* __restrict__ rowptr,
                                                   const int* __restrict__ blockSums, int n) {
    int i = blockIdx.x * THREADS + threadIdx.x;
    if (i < n) rowptr[i] += blockSums[i >> 10];
}

// cursor must be zeroed before. srcSorted[rowptr[d] + slot] = src[e]
__global__ __launch_bounds__(THREADS) void k_scatter(const int* __restrict__ src,
                                                     const int* __restrict__ dst,
                                                     const int* __restrict__ rowptr,
                                                     int* __restrict__ cursor,
                                                     int* __restrict__ srcSorted, int E) {
    int e = blockIdx.x * THREADS + threadIdx.x;
    if (e >= E) return;
    int d = dst[e];
    int pos = rowptr[d] + atomicAdd(&cursor[d], 1);
    srcSorted[pos] = src[e];
}

// ================= GEMM: C[M][128] = A[M][128] @ B[128][128] =================
__global__ __launch_bounds__(THREADS) void k_gemm128(const float* __restrict__ A,
                                                     const float* __restrict__ B,
                                                     float* __restrict__ C, int M) {
    __shared__ float4 As[64][8];
    __shared__ float4 Bs[32][32];

    int tid = threadIdx.x;
    int tx = tid & 31;
    int ty = tid >> 5;
    int row0 = blockIdx.x * 64;

    float4 acc[8];
#pragma unroll
    for (int i = 0; i < 8; i++) acc[i] = make_float4(0.f, 0.f, 0.f, 0.f);

    for (int k0 = 0; k0 < 128; k0 += 32) {
#pragma unroll
        for (int i = 0; i < 2; i++) {
            int idx = tid + i * 256;
            int r = idx >> 3, q = idx & 7;
            int row = row0 + r;
            float4 v = make_float4(0.f, 0.f, 0.f, 0.f);
            if (row < M) v = *(const float4*)(A + (size_t)row * 128 + k0 + q * 4);
            As[r][q] = v;
        }
#pragma unroll
        for (int i = 0; i < 4; i++) {
            int idx = tid + i * 256;
            int r = idx >> 5, c4 = idx & 31;
            Bs[r][c4] = *(const float4*)(B + (size_t)(k0 + r) * 128 + c4 * 4);
        }
        __syncthreads();

#pragma unroll
        for (int k4 = 0; k4 < 8; k4++) {
            float4 b0 = Bs[k4 * 4 + 0][tx];
            float4 b1 = Bs[k4 * 4 + 1][tx];
            float4 b2 = Bs[k4 * 4 + 2][tx];
            float4 b3 = Bs[k4 * 4 + 3][tx];
#pragma unroll
            for (int i = 0; i < 8; i++) {
                float4 a = As[ty * 8 + i][k4];
                acc[i].x = fmaf(a.x, b0.x, fmaf(a.y, b1.x, fmaf(a.z, b2.x, fmaf(a.w, b3.x, acc[i].x))));
                acc[i].y = fmaf(a.x, b0.y, fmaf(a.y, b1.y, fmaf(a.z, b2.y, fmaf(a.w, b3.y, acc[i].y))));
                acc[i].z = fmaf(a.x, b0.z, fmaf(a.y, b1.z, fmaf(a.z, b2.z, fmaf(a.w, b3.z, acc[i].z))));
                acc[i].w = fmaf(a.x, b0.w, fmaf(a.y, b1.w, fmaf(a.z, b2.w, fmaf(a.w, b3.w, acc[i].w))));
            }
        }
        __syncthreads();
    }

#pragma unroll
    for (int i = 0; i < 8; i++) {
        int row = row0 + ty * 8 + i;
        if (row < M) *(float4*)(C + (size_t)row * 128 + tx * 4) = acc[i];
    }
}

// ================= gather-aggregate (fused finalize) =================
// one wave per dst node; lane holds 2 channels (float2).
// h[node] = relu( di * sum_{s in nbrs} xw[s]*dinv[s]  +  di^2 * xw[node]  + b )
__global__ __launch_bounds__(THREADS) void k_gather_agg(const int* __restrict__ rowptr,
                                                        const int* __restrict__ srcSorted,
                                                        const float* __restrict__ xw,
                                                        const float* __restrict__ dinv,
                                                        const float* __restrict__ bias,
                                                        float* __restrict__ h, int n) {
    int node = blockIdx.x * 4 + (threadIdx.x >> 6);
    int lane = threadIdx.x & 63;
    if (node >= n) return;
    int beg = rowptr[node], end = rowptr[node + 1];
    float di = dinv[node];

    float ax = 0.f, ay = 0.f;
    int j = beg;
    for (; j + 3 < end; j += 4) {
        int s0 = srcSorted[j + 0];
        int s1 = srcSorted[j + 1];
        int s2 = srcSorted[j + 2];
        int s3 = srcSorted[j + 3];
        float w0 = dinv[s0], w1 = dinv[s1], w2 = dinv[s2], w3 = dinv[s3];
        float2 v0 = *(const float2*)(xw + (size_t)s0 * 128 + lane * 2);
        float2 v1 = *(const float2*)(xw + (size_t)s1 * 128 + lane * 2);
        float2 v2 = *(const float2*)(xw + (size_t)s2 * 128 + lane * 2);
        float2 v3 = *(const float2*)(xw + (size_t)s3 * 128 + lane * 2);
        ax = fmaf(v0.x, w0, fmaf(v1.x, w1, fmaf(v2.x, w2, fmaf(v3.x, w3, ax))));
        ay = fmaf(v0.y, w0, fmaf(v1.y, w1, fmaf(v2.y, w2, fmaf(v3.y, w3, ay))));
    }
    for (; j < end; ++j) {
        int s = srcSorted[j];
        float w = dinv[s];
        float2 v = *(const float2*)(xw + (size_t)s * 128 + lane * 2);
        ax = fmaf(v.x, w, ax);
        ay = fmaf(v.y, w, ay);
    }

    float2 xv = *(const float2*)(xw + (size_t)node * 128 + lane * 2);
    float2 b = *(const float2*)(bias + lane * 2);
    float dd = di * di;
    float rx = fmaxf(fmaf(ax, di, fmaf(xv.x, dd, b.x)), 0.f);
    float ry = fmaxf(fmaf(ay, di, fmaf(xv.y, dd, b.y)), 0.f);
    float2 r = make_float2(rx, ry);
    *(float2*)(h + (size_t)node * 128 + lane * 2) = r;
}

// ================= edge head =================
__global__ __launch_bounds__(THREADS) void k_edge_head(const int* __restrict__ src,
                                                       const int* __restrict__ dst,
                                                       const float* __restrict__ h,
                                                       const float* __restrict__ fc1w,
                                                       const float* __restrict__ fc1b,
                                                       const float* __restrict__ fc2w,
                                                       const float* __restrict__ fc2b,
                                                       float* __restrict__ out, int E) {
    __shared__ float4 ef[32][64];
    int tid = threadIdx.x;
    int e0 = blockIdx.x * 32;

#pragma unroll
    for (int i = 0; i < 4; i++) {
        int idx = tid + i * 256;
        int e = idx >> 5, c4 = idx & 31;
        int ee = e0 + e;
        float4 p = make_float4(0.f, 0.f, 0.f, 0.f);
        float4 dq = p;
        if (ee < E) {
            int s = src[ee], d = dst[ee];
            float4 xv = *(const float4*)(h + (size_t)s * 128 + c4 * 4);
            float4 yv = *(const float4*)(h + (size_t)d * 128 + c4 * 4);
            p  = make_float4(xv.x * yv.x, xv.y * yv.y, xv.z * yv.z, xv.w * yv.w);
            dq = make_float4(xv.x - yv.x, xv.y - yv.y, xv.z - yv.z, xv.w - yv.w);
        }
        ef[e][c4] = p;
        ef[e][32 + c4] = dq;
    }
    __syncthreads();

    int tx = tid & 31;
    int ty = tid >> 5;
    float4 acc[4];
#pragma unroll
    for (int i = 0; i < 4; i++) acc[i] = make_float4(0.f, 0.f, 0.f, 0.f);

#pragma unroll 2
    for (int k4 = 0; k4 < 64; k4++) {
        float4 w0 = *(const float4*)(fc1w + (size_t)(k4 * 4 + 0) * 128 + tx * 4);
        float4 w1 = *(const float4*)(fc1w + (size_t)(k4 * 4 + 1) * 128 + tx * 4);
        float4 w2 = *(const float4*)(fc1w + (size_t)(k4 * 4 + 2) * 128 + tx * 4);
        float4 w3 = *(const float4*)(fc1w + (size_t)(k4 * 4 + 3) * 128 + tx * 4);
#pragma unroll
        for (int i = 0; i < 4; i++) {
            float4 a = ef[ty * 4 + i][k4];
            acc[i].x = fmaf(a.x, w0.x, fmaf(a.y, w1.x, fmaf(a.z, w2.x, fmaf(a.w, w3.x, acc[i].x))));
            acc[i].y = fmaf(a.x, w0.y, fmaf(a.y, w1.y, fmaf(a.z, w2.y, fmaf(a.w, w3.y, acc[i].y))));
            acc[i].z = fmaf(a.x, w0.z, fmaf(a.y, w1.z, fmaf(a.z, w2.z, fmaf(a.w, w3.z, acc[i].z))));
            acc[i].w = fmaf(a.x, w0.w, fmaf(a.y, w1.w, fmaf(a.z, w2.w, fmaf(a.w, w3.w, acc[i].w))));
        }
    }

    float4 b1 = *(const float4*)(fc1b + tx * 4);
    float4 wv = *(const float4*)(fc2w + tx * 4);
    float bias2 = fc2b[0];

#pragma unroll
    for (int i = 0; i < 4; i++) {
        float zx = fmaxf(acc[i].x + b1.x, 0.f);
        float zy = fmaxf(acc[i].y + b1.y, 0.f);
        float zz = fmaxf(acc[i].z + b1.z, 0.f);
        float zw = fmaxf(acc[i].w + b1.w, 0.f);
        float part = zx * wv.x + zy * wv.y + zz * wv.z + zw * wv.w;
#pragma unroll
        for (int m = 16; m > 0; m >>= 1) part += __shfl_xor(part, m);
        if (tx == 0) {
            int ee = e0 + ty * 4 + i;
            if (ee < E) out[ee] = 1.0f / (1.0f + expf(-(part + bias2)));
        }
    }
}

// ================= host =================
extern "C" void kernel_launch(void* const* d_in, const int* in_sizes, int n_in,
                              void* d_out, int out_size, void* d_ws, size_t ws_size,
                              hipStream_t stream) {
    const float* x    = (const float*)d_in[0];
    const int*   ei   = (const int*)d_in[1];
    const float* W1   = (const float*)d_in[2];
    const float* b1   = (const float*)d_in[3];
    const float* W2   = (const float*)d_in[4];
    const float* b2   = (const float*)d_in[5];
    const float* fc1w = (const float*)d_in[6];
    const float* fc1b = (const float*)d_in[7];
    const float* fc2w = (const float*)d_in[8];
    const float* fc2b = (const float*)d_in[9];

    int N = in_sizes[0] / 128;
    int E = in_sizes[1] / 2;
    const int* src = ei;
    const int* dst = ei + E;

    // ---- workspace layout ----
    char* ws = (char*)d_ws;
    size_t off = 0;
    auto alloc = [&](size_t bytes) { char* p = ws + off; off += (bytes + 255) & ~(size_t)255; return p; };
    int*   cnt       = (int*)  alloc((size_t)N * 4);
    int*   rowptr    = (int*)  alloc(((size_t)N + 1) * 4);
    int*   cursor    = (int*)  alloc((size_t)N * 4);
    int*   blockSums = (int*)  alloc(256 * 4);
    int*   srcSorted = (int*)  alloc((size_t)E * 4);
    float* dinv      = (float*)alloc((size_t)N * 4);
    float* xw        = (float*)alloc((size_t)N * 128 * 4);
    float* h         = (float*)alloc((size_t)N * 128 * 4);

    int gN     = (N + THREADS - 1) / THREADS;
    int gE     = (E + THREADS - 1) / THREADS;
    int nchunk = (N + 1023) / 1024;
    int gGemm  = (N + 63) / 64;
    int gGath  = (N + 3) / 4;
    int gHead  = (E + 31) / 32;

    // ---- CSR build + degrees ----
    hipMemsetAsync(cnt, 0, (size_t)N * 4, stream);
    k_hist<<<gE, THREADS, 0, stream>>>(dst, cnt, E);
    k_dinv<<<gN, THREADS, 0, stream>>>(cnt, dinv, N);
    k_scan1<<<nchunk, THREADS, 0, stream>>>(cnt, rowptr, blockSums, N);
    k_scan2<<<1, THREADS, 0, stream>>>(blockSums, rowptr, nchunk, N, E);
    k_scan3<<<gN, THREADS, 0, stream>>>(rowptr, blockSums, N);
    hipMemsetAsync(cursor, 0, (size_t)N * 4, stream);
    k_scatter<<<gE, THREADS, 0, stream>>>(src, dst, rowptr, cursor, srcSorted, E);

    // ---- layer 1 ----
    k_gemm128<<<gGemm, THREADS, 0, stream>>>(x, W1, xw, N);
    k_gather_agg<<<gGath, THREADS, 0, stream>>>(rowptr, srcSorted, xw, dinv, b1, h, N);

    // ---- layer 2 ----
    k_gemm128<<<gGemm, THREADS, 0, stream>>>(h, W2, xw, N);
    k_gather_agg<<<gGath, THREADS, 0, stream>>>(rowptr, srcSorted, xw, dinv, b2, h, N);

    // ---- edge head ----
    k_edge_head<<<gHead, THREADS, 0, stream>>>(src, dst, h, fc1w, fc1b, fc2w, fc2b,
                                               (float*)d_out, E);
}

// Round 3
// 918.950 us; speedup vs baseline: 8.0660x; 2.2318x over previous
//
#include <hip/hip_runtime.h>

#define THREADS 256

typedef __bf16 bf16x8 __attribute__((ext_vector_type(8)));
typedef float  f32x4  __attribute__((ext_vector_type(4)));

// ================= CSR build: histogram -> scan -> scatter =================

__global__ __launch_bounds__(THREADS) void k_hist(const int* __restrict__ dst,
                                                  int* __restrict__ cnt, int E) {
    int e = blockIdx.x * THREADS + threadIdx.x;
    if (e < E) atomicAdd(&cnt[dst[e]], 1);
}

__global__ __launch_bounds__(THREADS) void k_dinv(const int* __restrict__ cnt,
                                                  float* __restrict__ dinv, int n) {
    int i = blockIdx.x * THREADS + threadIdx.x;
    if (i < n) dinv[i] = rsqrtf((float)cnt[i] + 1.0f);
}

__global__ __launch_bounds__(THREADS) void k_scan1(const int* __restrict__ cnt,
                                                   int* __restrict__ rowptr,
                                                   int* __restrict__ blockSums, int n) {
    __shared__ int part[THREADS];
    int tid = threadIdx.x;
    int base = blockIdx.x * 1024 + tid * 4;
    int v0 = (base + 0 < n) ? cnt[base + 0] : 0;
    int v1 = (base + 1 < n) ? cnt[base + 1] : 0;
    int v2 = (base + 2 < n) ? cnt[base + 2] : 0;
    int v3 = (base + 3 < n) ? cnt[base + 3] : 0;
    part[tid] = v0 + v1 + v2 + v3;
    __syncthreads();
    for (int off = 1; off < THREADS; off <<= 1) {
        int t = 0;
        if (tid >= off) t = part[tid - off];
        __syncthreads();
        if (tid >= off) part[tid] += t;
        __syncthreads();
    }
    int excl = (tid == 0) ? 0 : part[tid - 1];
    if (tid == THREADS - 1) blockSums[blockIdx.x] = part[THREADS - 1];
    int run = excl;
    if (base + 0 < n) rowptr[base + 0] = run; run += v0;
    if (base + 1 < n) rowptr[base + 1] = run; run += v1;
    if (base + 2 < n) rowptr[base + 2] = run; run += v2;
    if (base + 3 < n) rowptr[base + 3] = run;
}

__global__ __launch_bounds__(THREADS) void k_scan2(int* __restrict__ blockSums,
                                                   int* __restrict__ rowptr,
                                                   int nchunks, int n, int E) {
    __shared__ int part[THREADS];
    int tid = threadIdx.x;
    int v = (tid < nchunks) ? blockSums[tid] : 0;
    part[tid] = v;
    __syncthreads();
    for (int off = 1; off < THREADS; off <<= 1) {
        int t = 0;
        if (tid >= off) t = part[tid - off];
        __syncthreads();
        if (tid >= off) part[tid] += t;
        __syncthreads();
    }
    int excl = (tid == 0) ? 0 : part[tid - 1];
    if (tid < nchunks) blockSums[tid] = excl;
    if (tid == 0) rowptr[n] = E;
}

__global__ __launch_bounds__(THREADS) void k_scan3(int* __restrict__ rowptr,
                                                   const int* __restrict__ blockSums, int n) {
    int i = blockIdx.x * THREADS + threadIdx.x;
    if (i < n) rowptr[i] += blockSums[i >> 10];
}

__global__ __launch_bounds__(THREADS) void k_scatter(const int* __restrict__ src,
                                                     const int* __restrict__ dst,
                                                     const int* __restrict__ rowptr,
                                                     int* __restrict__ cursor,
                                                     int* __restrict__ srcSorted, int E) {
    int e = blockIdx.x * THREADS + threadIdx.x;
    if (e >= E) return;
    int d = dst[e];
    int pos = rowptr[d] + atomicAdd(&cursor[d], 1);
    srcSorted[pos] = src[e];
}

// ================= GEMM: C[M][128] = A[M][128] @ B[128][128] =================
__global__ __launch_bounds__(THREADS) void k_gemm128(const float* __restrict__ A,
                                                     const float* __restrict__ B,
                                                     float* __restrict__ C, int M) {
    __shared__ float4 As[64][8];
    __shared__ float4 Bs[32][32];

    int tid = threadIdx.x;
    int tx = tid & 31;
    int ty = tid >> 5;
    int row0 = blockIdx.x * 64;

    float4 acc[8];
#pragma unroll
    for (int i = 0; i < 8; i++) acc[i] = make_float4(0.f, 0.f, 0.f, 0.f);

    for (int k0 = 0; k0 < 128; k0 += 32) {
#pragma unroll
        for (int i = 0; i < 2; i++) {
            int idx = tid + i * 256;
            int r = idx >> 3, q = idx & 7;
            int row = row0 + r;
            float4 v = make_float4(0.f, 0.f, 0.f, 0.f);
            if (row < M) v = *(const float4*)(A + (size_t)row * 128 + k0 + q * 4);
            As[r][q] = v;
        }
#pragma unroll
        for (int i = 0; i < 4; i++) {
            int idx = tid + i * 256;
            int r = idx >> 5, c4 = idx & 31;
            Bs[r][c4] = *(const float4*)(B + (size_t)(k0 + r) * 128 + c4 * 4);
        }
        __syncthreads();

#pragma unroll
        for (int k4 = 0; k4 < 8; k4++) {
            float4 b0 = Bs[k4 * 4 + 0][tx];
            float4 b1 = Bs[k4 * 4 + 1][tx];
            float4 b2 = Bs[k4 * 4 + 2][tx];
            float4 b3 = Bs[k4 * 4 + 3][tx];
#pragma unroll
            for (int i = 0; i < 8; i++) {
                float4 a = As[ty * 8 + i][k4];
                acc[i].x = fmaf(a.x, b0.x, fmaf(a.y, b1.x, fmaf(a.z, b2.x, fmaf(a.w, b3.x, acc[i].x))));
                acc[i].y = fmaf(a.x, b0.y, fmaf(a.y, b1.y, fmaf(a.z, b2.y, fmaf(a.w, b3.y, acc[i].y))));
                acc[i].z = fmaf(a.x, b0.z, fmaf(a.y, b1.z, fmaf(a.z, b2.z, fmaf(a.w, b3.z, acc[i].z))));
                acc[i].w = fmaf(a.x, b0.w, fmaf(a.y, b1.w, fmaf(a.z, b2.w, fmaf(a.w, b3.w, acc[i].w))));
            }
        }
        __syncthreads();
    }

#pragma unroll
    for (int i = 0; i < 8; i++) {
        int row = row0 + ty * 8 + i;
        if (row < M) *(float4*)(C + (size_t)row * 128 + tx * 4) = acc[i];
    }
}

// ================= gather-aggregate (fused finalize) =================
__global__ __launch_bounds__(THREADS) void k_gather_agg(const int* __restrict__ rowptr,
                                                        const int* __restrict__ srcSorted,
                                                        const float* __restrict__ xw,
                                                        const float* __restrict__ dinv,
                                                        const float* __restrict__ bias,
                                                        float* __restrict__ h, int n) {
    int node = blockIdx.x * 4 + (threadIdx.x >> 6);
    int lane = threadIdx.x & 63;
    if (node >= n) return;
    int beg = rowptr[node], end = rowptr[node + 1];
    float di = dinv[node];

    float ax = 0.f, ay = 0.f;
    int j = beg;
    for (; j + 3 < end; j += 4) {
        int s0 = srcSorted[j + 0];
        int s1 = srcSorted[j + 1];
        int s2 = srcSorted[j + 2];
        int s3 = srcSorted[j + 3];
        float w0 = dinv[s0], w1 = dinv[s1], w2 = dinv[s2], w3 = dinv[s3];
        float2 v0 = *(const float2*)(xw + (size_t)s0 * 128 + lane * 2);
        float2 v1 = *(const float2*)(xw + (size_t)s1 * 128 + lane * 2);
        float2 v2 = *(const float2*)(xw + (size_t)s2 * 128 + lane * 2);
        float2 v3 = *(const float2*)(xw + (size_t)s3 * 128 + lane * 2);
        ax = fmaf(v0.x, w0, fmaf(v1.x, w1, fmaf(v2.x, w2, fmaf(v3.x, w3, ax))));
        ay = fmaf(v0.y, w0, fmaf(v1.y, w1, fmaf(v2.y, w2, fmaf(v3.y, w3, ay))));
    }
    for (; j < end; ++j) {
        int s = srcSorted[j];
        float w = dinv[s];
        float2 v = *(const float2*)(xw + (size_t)s * 128 + lane * 2);
        ax = fmaf(v.x, w, ax);
        ay = fmaf(v.y, w, ay);
    }

    float2 xv = *(const float2*)(xw + (size_t)node * 128 + lane * 2);
    float2 b = *(const float2*)(bias + lane * 2);
    float dd = di * di;
    float rx = fmaxf(fmaf(ax, di, fmaf(xv.x, dd, b.x)), 0.f);
    float ry = fmaxf(fmaf(ay, di, fmaf(xv.y, dd, b.y)), 0.f);
    float2 r = make_float2(rx, ry);
    *(float2*)(h + (size_t)node * 128 + lane * 2) = r;
}

// ================= B-pack: fc1w [256][128] f32 -> MFMA B-fragments bf16 =================
// frag index f = (ks*8+nt)*64 + lane ; element i:
//   bpack[f*8+i] = fc1w[ks*32 + (lane>>4)*8 + i][nt*16 + (lane&15)]
__global__ __launch_bounds__(THREADS) void k_pack_b(const float* __restrict__ fc1w,
                                                    __bf16* __restrict__ bpack) {
    int t = blockIdx.x * THREADS + threadIdx.x;   // 0..4095
    int lane = t & 63;
    int fi = t >> 6;          // ks*8+nt
    int nt = fi & 7, ks = fi >> 3;
    int krow = ks * 32 + (lane >> 4) * 8;
    int col = nt * 16 + (lane & 15);
    bf16x8 v;
#pragma unroll
    for (int i = 0; i < 8; i++) v[i] = (__bf16)fc1w[(size_t)(krow + i) * 128 + col];
    *(bf16x8*)(bpack + (size_t)t * 8) = v;
}

// ================= edge head (MFMA) =================
// 4 waves/block, 16 edges/wave, 64 edges/block.
// A (ef, 16x256) built in registers; B from bpack (L2-resident); D: 8 n-tiles.
__global__ __launch_bounds__(THREADS) void k_edge_head_mfma(const int* __restrict__ src,
                                                            const int* __restrict__ dst,
                                                            const float* __restrict__ h,
                                                            const __bf16* __restrict__ bpack,
                                                            const float* __restrict__ fc1b,
                                                            const float* __restrict__ fc2w,
                                                            const float* __restrict__ fc2b,
                                                            float* __restrict__ out, int E) {
    int tid = threadIdx.x;
    int w = tid >> 6;
    int lane = tid & 63;
    int m = lane & 15;        // A row (edge within wave)
    int kg = lane >> 4;       // k-group: k = ks*32 + kg*8 + i
    int e0w = blockIdx.x * 64 + w * 16;
    int e = e0w + m;
    bool valid = e < E;
    int s = valid ? src[e] : 0;
    int d = valid ? dst[e] : 0;
    const float* px = h + (size_t)s * 128 + kg * 8;
    const float* py = h + (size_t)d * 128 + kg * 8;

    // A fragments: afrag[ks<4] = (x*y) cols, afrag[4+j] = (x-y) cols
    bf16x8 afrag[8];
#pragma unroll
    for (int j = 0; j < 4; j++) {
        float4 x0 = *(const float4*)(px + j * 32);
        float4 x1 = *(const float4*)(px + j * 32 + 4);
        float4 y0 = *(const float4*)(py + j * 32);
        float4 y1 = *(const float4*)(py + j * 32 + 4);
        bf16x8 p, q;
        p[0] = (__bf16)(x0.x * y0.x); q[0] = (__bf16)(x0.x - y0.x);
        p[1] = (__bf16)(x0.y * y0.y); q[1] = (__bf16)(x0.y - y0.y);
        p[2] = (__bf16)(x0.z * y0.z); q[2] = (__bf16)(x0.z - y0.z);
        p[3] = (__bf16)(x0.w * y0.w); q[3] = (__bf16)(x0.w - y0.w);
        p[4] = (__bf16)(x1.x * y1.x); q[4] = (__bf16)(x1.x - y1.x);
        p[5] = (__bf16)(x1.y * y1.y); q[5] = (__bf16)(x1.y - y1.y);
        p[6] = (__bf16)(x1.z * y1.z); q[6] = (__bf16)(x1.z - y1.z);
        p[7] = (__bf16)(x1.w * y1.w); q[7] = (__bf16)(x1.w - y1.w);
        afrag[j] = p;
        afrag[j + 4] = q;
    }

    f32x4 acc[8];
#pragma unroll
    for (int i = 0; i < 8; i++) acc[i] = (f32x4){0.f, 0.f, 0.f, 0.f};

    const bf16x8* bfr = ((const bf16x8*)bpack) + lane;
#pragma unroll
    for (int ks = 0; ks < 8; ks++) {
#pragma unroll
        for (int nt = 0; nt < 8; nt++) {
            bf16x8 b = bfr[(size_t)(ks * 8 + nt) * 64];
            acc[nt] = __builtin_amdgcn_mfma_f32_16x16x32_bf16(afrag[ks], b, acc[nt], 0, 0, 0);
        }
    }

    // epilogue: lane holds cols n = nt*16 + (lane&15), rows m = (lane>>4)*4 + r
    int n0 = lane & 15;
    int rowg = lane >> 4;
    float partial[4] = {0.f, 0.f, 0.f, 0.f};
#pragma unroll
    for (int nt = 0; nt < 8; nt++) {
        float bb = fc1b[nt * 16 + n0];
        float ww = fc2w[nt * 16 + n0];
#pragma unroll
        for (int r = 0; r < 4; r++) {
            float z = fmaxf(acc[nt][r] + bb, 0.f);
            partial[r] = fmaf(z, ww, partial[r]);
        }
    }
#pragma unroll
    for (int r = 0; r < 4; r++) {
        partial[r] += __shfl_xor(partial[r], 1);
        partial[r] += __shfl_xor(partial[r], 2);
        partial[r] += __shfl_xor(partial[r], 4);
        partial[r] += __shfl_xor(partial[r], 8);
    }
    if (n0 == 0) {
        float b2 = fc2b[0];
#pragma unroll
        for (int r = 0; r < 4; r++) {
            int ee = e0w + rowg * 4 + r;
            if (ee < E) out[ee] = 1.0f / (1.0f + expf(-(partial[r] + b2)));
        }
    }
}

// ================= host =================
extern "C" void kernel_launch(void* const* d_in, const int* in_sizes, int n_in,
                              void* d_out, int out_size, void* d_ws, size_t ws_size,
                              hipStream_t stream) {
    const float* x    = (const float*)d_in[0];
    const int*   ei   = (const int*)d_in[1];
    const float* W1   = (const float*)d_in[2];
    const float* b1   = (const float*)d_in[3];
    const float* W2   = (const float*)d_in[4];
    const float* b2   = (const float*)d_in[5];
    const float* fc1w = (const float*)d_in[6];
    const float* fc1b = (const float*)d_in[7];
    const float* fc2w = (const float*)d_in[8];
    const float* fc2b = (const float*)d_in[9];

    int N = in_sizes[0] / 128;
    int E = in_sizes[1] / 2;
    const int* src = ei;
    const int* dst = ei + E;

    // ---- workspace layout ----
    char* ws = (char*)d_ws;
    size_t off = 0;
    auto alloc = [&](size_t bytes) { char* p = ws + off; off += (bytes + 255) & ~(size_t)255; return p; };
    int*    cnt       = (int*)   alloc((size_t)N * 4);
    int*    rowptr    = (int*)   alloc(((size_t)N + 1) * 4);
    int*    cursor    = (int*)   alloc((size_t)N * 4);
    int*    blockSums = (int*)   alloc(256 * 4);
    int*    srcSorted = (int*)   alloc((size_t)E * 4);
    float*  dinv      = (float*) alloc((size_t)N * 4);
    __bf16* bpack     = (__bf16*)alloc((size_t)4096 * 8 * 2);     // 64 KB
    float*  xw        = (float*) alloc((size_t)N * 128 * 4);
    float*  h         = (float*) alloc((size_t)N * 128 * 4);

    int gN     = (N + THREADS - 1) / THREADS;
    int gE     = (E + THREADS - 1) / THREADS;
    int nchunk = (N + 1023) / 1024;
    int gGemm  = (N + 63) / 64;
    int gGath  = (N + 3) / 4;
    int gHead  = (E + 63) / 64;

    // ---- CSR build + degrees + B-pack ----
    hipMemsetAsync(cnt, 0, (size_t)N * 4, stream);
    k_hist<<<gE, THREADS, 0, stream>>>(dst, cnt, E);
    k_dinv<<<gN, THREADS, 0, stream>>>(cnt, dinv, N);
    k_scan1<<<nchunk, THREADS, 0, stream>>>(cnt, rowptr, blockSums, N);
    k_scan2<<<1, THREADS, 0, stream>>>(blockSums, rowptr, nchunk, N, E);
    k_scan3<<<gN, THREADS, 0, stream>>>(rowptr, blockSums, N);
    hipMemsetAsync(cursor, 0, (size_t)N * 4, stream);
    k_scatter<<<gE, THREADS, 0, stream>>>(src, dst, rowptr, cursor, srcSorted, E);
    k_pack_b<<<16, THREADS, 0, stream>>>(fc1w, bpack);

    // ---- layer 1 ----
    k_gemm128<<<gGemm, THREADS, 0, stream>>>(x, W1, xw, N);
    k_gather_agg<<<gGath, THREADS, 0, stream>>>(rowptr, srcSorted, xw, dinv, b1, h, N);

    // ---- layer 2 ----
    k_gemm128<<<gGemm, THREADS, 0, stream>>>(h, W2, xw, N);
    k_gather_agg<<<gGath, THREADS, 0, stream>>>(rowptr, srcSorted, xw, dinv, b2, h, N);

    // ---- edge head (MFMA) ----
    k_edge_head_mfma<<<gHead, THREADS, 0, stream>>>(src, dst, h, bpack, fc1b, fc2w, fc2b,
                                                    (float*)d_out, E);
}

// Round 4
// 837.723 us; speedup vs baseline: 8.8481x; 1.0970x over previous
//
#include <hip/hip_runtime.h>

#define THREADS 256

typedef __bf16 bf16x8 __attribute__((ext_vector_type(8)));
typedef float  f32x4  __attribute__((ext_vector_type(4)));

// ================= CSR build: histogram -> scan -> scatter =================

__global__ __launch_bounds__(THREADS) void k_hist(const int* __restrict__ dst,
                                                  int* __restrict__ cnt, int E) {
    int e = blockIdx.x * THREADS + threadIdx.x;
    if (e < E) atomicAdd(&cnt[dst[e]], 1);
}

__global__ __launch_bounds__(THREADS) void k_dinv(const int* __restrict__ cnt,
                                                  float* __restrict__ dinv, int n) {
    int i = blockIdx.x * THREADS + threadIdx.x;
    if (i < n) dinv[i] = rsqrtf((float)cnt[i] + 1.0f);
}

__global__ __launch_bounds__(THREADS) void k_scan1(const int* __restrict__ cnt,
                                                   int* __restrict__ rowptr,
                                                   int* __restrict__ blockSums, int n) {
    __shared__ int part[THREADS];
    int tid = threadIdx.x;
    int base = blockIdx.x * 1024 + tid * 4;
    int v0 = (base + 0 < n) ? cnt[base + 0] : 0;
    int v1 = (base + 1 < n) ? cnt[base + 1] : 0;
    int v2 = (base + 2 < n) ? cnt[base + 2] : 0;
    int v3 = (base + 3 < n) ? cnt[base + 3] : 0;
    part[tid] = v0 + v1 + v2 + v3;
    __syncthreads();
    for (int off = 1; off < THREADS; off <<= 1) {
        int t = 0;
        if (tid >= off) t = part[tid - off];
        __syncthreads();
        if (tid >= off) part[tid] += t;
        __syncthreads();
    }
    int excl = (tid == 0) ? 0 : part[tid - 1];
    if (tid == THREADS - 1) blockSums[blockIdx.x] = part[THREADS - 1];
    int run = excl;
    if (base + 0 < n) rowptr[base + 0] = run; run += v0;
    if (base + 1 < n) rowptr[base + 1] = run; run += v1;
    if (base + 2 < n) rowptr[base + 2] = run; run += v2;
    if (base + 3 < n) rowptr[base + 3] = run;
}

__global__ __launch_bounds__(THREADS) void k_scan2(int* __restrict__ blockSums,
                                                   int* __restrict__ rowptr,
                                                   int nchunks, int n, int E) {
    __shared__ int part[THREADS];
    int tid = threadIdx.x;
    int v = (tid < nchunks) ? blockSums[tid] : 0;
    part[tid] = v;
    __syncthreads();
    for (int off = 1; off < THREADS; off <<= 1) {
        int t = 0;
        if (tid >= off) t = part[tid - off];
        __syncthreads();
        if (tid >= off) part[tid] += t;
        __syncthreads();
    }
    int excl = (tid == 0) ? 0 : part[tid - 1];
    if (tid < nchunks) blockSums[tid] = excl;
    if (tid == 0) rowptr[n] = E;
}

__global__ __launch_bounds__(THREADS) void k_scan3(int* __restrict__ rowptr,
                                                   const int* __restrict__ blockSums, int n) {
    int i = blockIdx.x * THREADS + threadIdx.x;
    if (i < n) rowptr[i] += blockSums[i >> 10];
}

// also records dstSorted + original edge id (for permuted output write)
__global__ __launch_bounds__(THREADS) void k_scatter(const int* __restrict__ src,
                                                     const int* __restrict__ dst,
                                                     const int* __restrict__ rowptr,
                                                     int* __restrict__ cursor,
                                                     int* __restrict__ srcSorted,
                                                     int* __restrict__ dstSorted,
                                                     int* __restrict__ edgePerm, int E) {
    int e = blockIdx.x * THREADS + threadIdx.x;
    if (e >= E) return;
    int d = dst[e];
    int pos = rowptr[d] + atomicAdd(&cursor[d], 1);
    srcSorted[pos] = src[e];
    dstSorted[pos] = d;
    edgePerm[pos] = e;
}

// ================= GEMM: C[M][128] = A[M][128] @ B[128][128] =================
__global__ __launch_bounds__(THREADS) void k_gemm128(const float* __restrict__ A,
                                                     const float* __restrict__ B,
                                                     float* __restrict__ C, int M) {
    __shared__ float4 As[64][8];
    __shared__ float4 Bs[32][32];

    int tid = threadIdx.x;
    int tx = tid & 31;
    int ty = tid >> 5;
    int row0 = blockIdx.x * 64;

    float4 acc[8];
#pragma unroll
    for (int i = 0; i < 8; i++) acc[i] = make_float4(0.f, 0.f, 0.f, 0.f);

    for (int k0 = 0; k0 < 128; k0 += 32) {
#pragma unroll
        for (int i = 0; i < 2; i++) {
            int idx = tid + i * 256;
            int r = idx >> 3, q = idx & 7;
            int row = row0 + r;
            float4 v = make_float4(0.f, 0.f, 0.f, 0.f);
            if (row < M) v = *(const float4*)(A + (size_t)row * 128 + k0 + q * 4);
            As[r][q] = v;
        }
#pragma unroll
        for (int i = 0; i < 4; i++) {
            int idx = tid + i * 256;
            int r = idx >> 5, c4 = idx & 31;
            Bs[r][c4] = *(const float4*)(B + (size_t)(k0 + r) * 128 + c4 * 4);
        }
        __syncthreads();

#pragma unroll
        for (int k4 = 0; k4 < 8; k4++) {
            float4 b0 = Bs[k4 * 4 + 0][tx];
            float4 b1 = Bs[k4 * 4 + 1][tx];
            float4 b2 = Bs[k4 * 4 + 2][tx];
            float4 b3 = Bs[k4 * 4 + 3][tx];
#pragma unroll
            for (int i = 0; i < 8; i++) {
                float4 a = As[ty * 8 + i][k4];
                acc[i].x = fmaf(a.x, b0.x, fmaf(a.y, b1.x, fmaf(a.z, b2.x, fmaf(a.w, b3.x, acc[i].x))));
                acc[i].y = fmaf(a.x, b0.y, fmaf(a.y, b1.y, fmaf(a.z, b2.y, fmaf(a.w, b3.y, acc[i].y))));
                acc[i].z = fmaf(a.x, b0.z, fmaf(a.y, b1.z, fmaf(a.z, b2.z, fmaf(a.w, b3.z, acc[i].z))));
                acc[i].w = fmaf(a.x, b0.w, fmaf(a.y, b1.w, fmaf(a.z, b2.w, fmaf(a.w, b3.w, acc[i].w))));
            }
        }
        __syncthreads();
    }

#pragma unroll
    for (int i = 0; i < 8; i++) {
        int row = row0 + ty * 8 + i;
        if (row < M) *(float4*)(C + (size_t)row * 128 + tx * 4) = acc[i];
    }
}

// ================= gather-aggregate (fused finalize) =================
__global__ __launch_bounds__(THREADS) void k_gather_agg(const int* __restrict__ rowptr,
                                                        const int* __restrict__ srcSorted,
                                                        const float* __restrict__ xw,
                                                        const float* __restrict__ dinv,
                                                        const float* __restrict__ bias,
                                                        float* __restrict__ h, int n) {
    int node = blockIdx.x * 4 + (threadIdx.x >> 6);
    int lane = threadIdx.x & 63;
    if (node >= n) return;
    int beg = rowptr[node], end = rowptr[node + 1];
    float di = dinv[node];

    float ax = 0.f, ay = 0.f;
    int j = beg;
    for (; j + 7 < end; j += 8) {
        int sI[8];
        float wI[8];
        float2 vI[8];
#pragma unroll
        for (int q = 0; q < 8; q++) sI[q] = srcSorted[j + q];
#pragma unroll
        for (int q = 0; q < 8; q++) wI[q] = dinv[sI[q]];
#pragma unroll
        for (int q = 0; q < 8; q++) vI[q] = *(const float2*)(xw + (size_t)sI[q] * 128 + lane * 2);
#pragma unroll
        for (int q = 0; q < 8; q++) {
            ax = fmaf(vI[q].x, wI[q], ax);
            ay = fmaf(vI[q].y, wI[q], ay);
        }
    }
    for (; j + 3 < end; j += 4) {
        int s0 = srcSorted[j + 0];
        int s1 = srcSorted[j + 1];
        int s2 = srcSorted[j + 2];
        int s3 = srcSorted[j + 3];
        float w0 = dinv[s0], w1 = dinv[s1], w2 = dinv[s2], w3 = dinv[s3];
        float2 v0 = *(const float2*)(xw + (size_t)s0 * 128 + lane * 2);
        float2 v1 = *(const float2*)(xw + (size_t)s1 * 128 + lane * 2);
        float2 v2 = *(const float2*)(xw + (size_t)s2 * 128 + lane * 2);
        float2 v3 = *(const float2*)(xw + (size_t)s3 * 128 + lane * 2);
        ax = fmaf(v0.x, w0, fmaf(v1.x, w1, fmaf(v2.x, w2, fmaf(v3.x, w3, ax))));
        ay = fmaf(v0.y, w0, fmaf(v1.y, w1, fmaf(v2.y, w2, fmaf(v3.y, w3, ay))));
    }
    for (; j < end; ++j) {
        int s = srcSorted[j];
        float w = dinv[s];
        float2 v = *(const float2*)(xw + (size_t)s * 128 + lane * 2);
        ax = fmaf(v.x, w, ax);
        ay = fmaf(v.y, w, ay);
    }

    float2 xv = *(const float2*)(xw + (size_t)node * 128 + lane * 2);
    float2 b = *(const float2*)(bias + lane * 2);
    float dd = di * di;
    float rx = fmaxf(fmaf(ax, di, fmaf(xv.x, dd, b.x)), 0.f);
    float ry = fmaxf(fmaf(ay, di, fmaf(xv.y, dd, b.y)), 0.f);
    float2 r = make_float2(rx, ry);
    *(float2*)(h + (size_t)node * 128 + lane * 2) = r;
}

// ================= B-pack: fc1w [256][128] f32 -> MFMA B-fragments bf16 =================
__global__ __launch_bounds__(THREADS) void k_pack_b(const float* __restrict__ fc1w,
                                                    __bf16* __restrict__ bpack) {
    int t = blockIdx.x * THREADS + threadIdx.x;   // 0..4095
    int lane = t & 63;
    int fi = t >> 6;          // ks*8+nt
    int nt = fi & 7, ks = fi >> 3;
    int krow = ks * 32 + (lane >> 4) * 8;
    int col = nt * 16 + (lane & 15);
    bf16x8 v;
#pragma unroll
    for (int i = 0; i < 8; i++) v[i] = (__bf16)fc1w[(size_t)(krow + i) * 128 + col];
    *(bf16x8*)(bpack + (size_t)t * 8) = v;
}

// ================= edge head (MFMA, dst-sorted order) =================
// 4 waves/block, 16 sorted-edges/wave. y=h[dst] rows are contiguous-duplicate in
// sorted order -> L1/L2 hits; x=h[src] random; output scattered via edgePerm.
__global__ __launch_bounds__(THREADS) void k_edge_head_mfma(const int* __restrict__ srcSorted,
                                                            const int* __restrict__ dstSorted,
                                                            const int* __restrict__ edgePerm,
                                                            const float* __restrict__ h,
                                                            const __bf16* __restrict__ bpack,
                                                            const float* __restrict__ fc1b,
                                                            const float* __restrict__ fc2w,
                                                            const float* __restrict__ fc2b,
                                                            float* __restrict__ out, int E) {
    int tid = threadIdx.x;
    int w = tid >> 6;
    int lane = tid & 63;
    int m = lane & 15;        // A row (edge within wave)
    int kg = lane >> 4;       // k-group: feature = kg*8 + j*32 + i
    int e0w = blockIdx.x * 64 + w * 16;
    int p = e0w + m;          // sorted position
    bool valid = p < E;
    int s = valid ? srcSorted[p] : 0;
    int d = valid ? dstSorted[p] : 0;
    const float* px = h + (size_t)s * 128 + kg * 8;
    const float* py = h + (size_t)d * 128 + kg * 8;

    // issue all global loads first (ILP), then convert
    float4 lx[8], ly[8];
#pragma unroll
    for (int j = 0; j < 4; j++) {
        lx[2 * j]     = *(const float4*)(px + j * 32);
        lx[2 * j + 1] = *(const float4*)(px + j * 32 + 4);
        ly[2 * j]     = *(const float4*)(py + j * 32);
        ly[2 * j + 1] = *(const float4*)(py + j * 32 + 4);
    }

    bf16x8 afrag[8];
#pragma unroll
    for (int j = 0; j < 4; j++) {
        float4 x0 = lx[2 * j], x1 = lx[2 * j + 1];
        float4 y0 = ly[2 * j], y1 = ly[2 * j + 1];
        bf16x8 pr, q;
        pr[0] = (__bf16)(x0.x * y0.x); q[0] = (__bf16)(x0.x - y0.x);
        pr[1] = (__bf16)(x0.y * y0.y); q[1] = (__bf16)(x0.y - y0.y);
        pr[2] = (__bf16)(x0.z * y0.z); q[2] = (__bf16)(x0.z - y0.z);
        pr[3] = (__bf16)(x0.w * y0.w); q[3] = (__bf16)(x0.w - y0.w);
        pr[4] = (__bf16)(x1.x * y1.x); q[4] = (__bf16)(x1.x - y1.x);
        pr[5] = (__bf16)(x1.y * y1.y); q[5] = (__bf16)(x1.y - y1.y);
        pr[6] = (__bf16)(x1.z * y1.z); q[6] = (__bf16)(x1.z - y1.z);
        pr[7] = (__bf16)(x1.w * y1.w); q[7] = (__bf16)(x1.w - y1.w);
        afrag[j] = pr;
        afrag[j + 4] = q;
    }

    f32x4 acc[8];
#pragma unroll
    for (int i = 0; i < 8; i++) acc[i] = (f32x4){0.f, 0.f, 0.f, 0.f};

    const bf16x8* bfr = ((const bf16x8*)bpack) + lane;
#pragma unroll
    for (int ks = 0; ks < 8; ks++) {
#pragma unroll
        for (int nt = 0; nt < 8; nt++) {
            bf16x8 b = bfr[(size_t)(ks * 8 + nt) * 64];
            acc[nt] = __builtin_amdgcn_mfma_f32_16x16x32_bf16(afrag[ks], b, acc[nt], 0, 0, 0);
        }
    }

    // epilogue: lane holds cols n = nt*16 + (lane&15), rows m = (lane>>4)*4 + r
    int n0 = lane & 15;
    int rowg = lane >> 4;
    float partial[4] = {0.f, 0.f, 0.f, 0.f};
#pragma unroll
    for (int nt = 0; nt < 8; nt++) {
        float bb = fc1b[nt * 16 + n0];
        float ww = fc2w[nt * 16 + n0];
#pragma unroll
        for (int r = 0; r < 4; r++) {
            float z = fmaxf(acc[nt][r] + bb, 0.f);
            partial[r] = fmaf(z, ww, partial[r]);
        }
    }
#pragma unroll
    for (int r = 0; r < 4; r++) {
        partial[r] += __shfl_xor(partial[r], 1);
        partial[r] += __shfl_xor(partial[r], 2);
        partial[r] += __shfl_xor(partial[r], 4);
        partial[r] += __shfl_xor(partial[r], 8);
    }
    if (n0 == 0) {
        float b2 = fc2b[0];
#pragma unroll
        for (int r = 0; r < 4; r++) {
            int q = e0w + rowg * 4 + r;
            if (q < E) out[edgePerm[q]] = 1.0f / (1.0f + expf(-(partial[r] + b2)));
        }
    }
}

// ================= host =================
extern "C" void kernel_launch(void* const* d_in, const int* in_sizes, int n_in,
                              void* d_out, int out_size, void* d_ws, size_t ws_size,
                              hipStream_t stream) {
    const float* x    = (const float*)d_in[0];
    const int*   ei   = (const int*)d_in[1];
    const float* W1   = (const float*)d_in[2];
    const float* b1   = (const float*)d_in[3];
    const float* W2   = (const float*)d_in[4];
    const float* b2   = (const float*)d_in[5];
    const float* fc1w = (const float*)d_in[6];
    const float* fc1b = (const float*)d_in[7];
    const float* fc2w = (const float*)d_in[8];
    const float* fc2b = (const float*)d_in[9];

    int N = in_sizes[0] / 128;
    int E = in_sizes[1] / 2;
    const int* src = ei;
    const int* dst = ei + E;

    // ---- workspace layout ----
    char* ws = (char*)d_ws;
    size_t off = 0;
    auto alloc = [&](size_t bytes) { char* p = ws + off; off += (bytes + 255) & ~(size_t)255; return p; };
    int*    cnt       = (int*)   alloc((size_t)N * 4);
    int*    rowptr    = (int*)   alloc(((size_t)N + 1) * 4);
    int*    cursor    = (int*)   alloc((size_t)N * 4);
    int*    blockSums = (int*)   alloc(256 * 4);
    int*    srcSorted = (int*)   alloc((size_t)E * 4);
    int*    dstSorted = (int*)   alloc((size_t)E * 4);
    int*    edgePerm  = (int*)   alloc((size_t)E * 4);
    float*  dinv      = (float*) alloc((size_t)N * 4);
    __bf16* bpack     = (__bf16*)alloc((size_t)4096 * 8 * 2);     // 64 KB
    float*  xw        = (float*) alloc((size_t)N * 128 * 4);
    float*  h         = (float*) alloc((size_t)N * 128 * 4);

    int gN     = (N + THREADS - 1) / THREADS;
    int gE     = (E + THREADS - 1) / THREADS;
    int nchunk = (N + 1023) / 1024;
    int gGemm  = (N + 63) / 64;
    int gGath  = (N + 3) / 4;
    int gHead  = (E + 63) / 64;

    // ---- CSR build + degrees + B-pack ----
    hipMemsetAsync(cnt, 0, (size_t)N * 4, stream);
    k_hist<<<gE, THREADS, 0, stream>>>(dst, cnt, E);
    k_dinv<<<gN, THREADS, 0, stream>>>(cnt, dinv, N);
    k_scan1<<<nchunk, THREADS, 0, stream>>>(cnt, rowptr, blockSums, N);
    k_scan2<<<1, THREADS, 0, stream>>>(blockSums, rowptr, nchunk, N, E);
    k_scan3<<<gN, THREADS, 0, stream>>>(rowptr, blockSums, N);
    hipMemsetAsync(cursor, 0, (size_t)N * 4, stream);
    k_scatter<<<gE, THREADS, 0, stream>>>(src, dst, rowptr, cursor,
                                          srcSorted, dstSorted, edgePerm, E);
    k_pack_b<<<16, THREADS, 0, stream>>>(fc1w, bpack);

    // ---- layer 1 ----
    k_gemm128<<<gGemm, THREADS, 0, stream>>>(x, W1, xw, N);
    k_gather_agg<<<gGath, THREADS, 0, stream>>>(rowptr, srcSorted, xw, dinv, b1, h, N);

    // ---- layer 2 ----
    k_gemm128<<<gGemm, THREADS, 0, stream>>>(h, W2, xw, N);
    k_gather_agg<<<gGath, THREADS, 0, stream>>>(rowptr, srcSorted, xw, dinv, b2, h, N);

    // ---- edge head (MFMA, sorted order) ----
    k_edge_head_mfma<<<gHead, THREADS, 0, stream>>>(srcSorted, dstSorted, edgePerm,
                                                    h, bpack, fc1b, fc2w, fc2b,
                                                    (float*)d_out, E);
}

// Round 5
// 795.989 us; speedup vs baseline: 9.3120x; 1.0524x over previous
//
#include <hip/hip_runtime.h>

#define THREADS 256

typedef __bf16 bf16x8 __attribute__((ext_vector_type(8)));
typedef __bf16 bf16x4 __attribute__((ext_vector_type(4)));
typedef float  f32x4  __attribute__((ext_vector_type(4)));

// ================= CSR build: histogram -> scan -> scatter =================

__global__ __launch_bounds__(THREADS) void k_hist(const int* __restrict__ dst,
                                                  int* __restrict__ cnt, int E) {
    int e = blockIdx.x * THREADS + threadIdx.x;
    if (e < E) atomicAdd(&cnt[dst[e]], 1);
}

__global__ __launch_bounds__(THREADS) void k_dinv(const int* __restrict__ cnt,
                                                  float* __restrict__ dinv, int n) {
    int i = blockIdx.x * THREADS + threadIdx.x;
    if (i < n) dinv[i] = rsqrtf((float)cnt[i] + 1.0f);
}

__global__ __launch_bounds__(THREADS) void k_scan1(const int* __restrict__ cnt,
                                                   int* __restrict__ rowptr,
                                                   int* __restrict__ blockSums, int n) {
    __shared__ int part[THREADS];
    int tid = threadIdx.x;
    int base = blockIdx.x * 1024 + tid * 4;
    int v0 = (base + 0 < n) ? cnt[base + 0] : 0;
    int v1 = (base + 1 < n) ? cnt[base + 1] : 0;
    int v2 = (base + 2 < n) ? cnt[base + 2] : 0;
    int v3 = (base + 3 < n) ? cnt[base + 3] : 0;
    part[tid] = v0 + v1 + v2 + v3;
    __syncthreads();
    for (int off = 1; off < THREADS; off <<= 1) {
        int t = 0;
        if (tid >= off) t = part[tid - off];
        __syncthreads();
        if (tid >= off) part[tid] += t;
        __syncthreads();
    }
    int excl = (tid == 0) ? 0 : part[tid - 1];
    if (tid == THREADS - 1) blockSums[blockIdx.x] = part[THREADS - 1];
    int run = excl;
    if (base + 0 < n) rowptr[base + 0] = run; run += v0;
    if (base + 1 < n) rowptr[base + 1] = run; run += v1;
    if (base + 2 < n) rowptr[base + 2] = run; run += v2;
    if (base + 3 < n) rowptr[base + 3] = run;
}

__global__ __launch_bounds__(THREADS) void k_scan2(int* __restrict__ blockSums,
                                                   int* __restrict__ rowptr,
                                                   int nchunks, int n, int E) {
    __shared__ int part[THREADS];
    int tid = threadIdx.x;
    int v = (tid < nchunks) ? blockSums[tid] : 0;
    part[tid] = v;
    __syncthreads();
    for (int off = 1; off < THREADS; off <<= 1) {
        int t = 0;
        if (tid >= off) t = part[tid - off];
        __syncthreads();
        if (tid >= off) part[tid] += t;
        __syncthreads();
    }
    int excl = (tid == 0) ? 0 : part[tid - 1];
    if (tid < nchunks) blockSums[tid] = excl;
    if (tid == 0) rowptr[n] = E;
}

__global__ __launch_bounds__(THREADS) void k_scan3(int* __restrict__ rowptr,
                                                   const int* __restrict__ blockSums, int n) {
    int i = blockIdx.x * THREADS + threadIdx.x;
    if (i < n) rowptr[i] += blockSums[i >> 10];
}

// writes: srcSorted (src id), swPair {src, dinv[src]}, dstSorted, edgePerm
__global__ __launch_bounds__(THREADS) void k_scatter(const int* __restrict__ src,
                                                     const int* __restrict__ dst,
                                                     const int* __restrict__ rowptr,
                                                     const float* __restrict__ dinv,
                                                     int* __restrict__ cursor,
                                                     int* __restrict__ srcSorted,
                                                     int2* __restrict__ swPair,
                                                     int* __restrict__ dstSorted,
                                                     int* __restrict__ edgePerm, int E) {
    int e = blockIdx.x * THREADS + threadIdx.x;
    if (e >= E) return;
    int d = dst[e];
    int s = src[e];
    int pos = rowptr[d] + atomicAdd(&cursor[d], 1);
    srcSorted[pos] = s;
    swPair[pos] = make_int2(s, __float_as_int(dinv[s]));
    dstSorted[pos] = d;
    edgePerm[pos] = e;
}

// ================= GEMM: C[M][128] = A[M][128] @ B[128][128] =================
__global__ __launch_bounds__(THREADS) void k_gemm128(const float* __restrict__ A,
                                                     const float* __restrict__ B,
                                                     float* __restrict__ C, int M) {
    __shared__ float4 As[64][8];
    __shared__ float4 Bs[32][32];

    int tid = threadIdx.x;
    int tx = tid & 31;
    int ty = tid >> 5;
    int row0 = blockIdx.x * 64;

    float4 acc[8];
#pragma unroll
    for (int i = 0; i < 8; i++) acc[i] = make_float4(0.f, 0.f, 0.f, 0.f);

    for (int k0 = 0; k0 < 128; k0 += 32) {
#pragma unroll
        for (int i = 0; i < 2; i++) {
            int idx = tid + i * 256;
            int r = idx >> 3, q = idx & 7;
            int row = row0 + r;
            float4 v = make_float4(0.f, 0.f, 0.f, 0.f);
            if (row < M) v = *(const float4*)(A + (size_t)row * 128 + k0 + q * 4);
            As[r][q] = v;
        }
#pragma unroll
        for (int i = 0; i < 4; i++) {
            int idx = tid + i * 256;
            int r = idx >> 5, c4 = idx & 31;
            Bs[r][c4] = *(const float4*)(B + (size_t)(k0 + r) * 128 + c4 * 4);
        }
        __syncthreads();

#pragma unroll
        for (int k4 = 0; k4 < 8; k4++) {
            float4 b0 = Bs[k4 * 4 + 0][tx];
            float4 b1 = Bs[k4 * 4 + 1][tx];
            float4 b2 = Bs[k4 * 4 + 2][tx];
            float4 b3 = Bs[k4 * 4 + 3][tx];
#pragma unroll
            for (int i = 0; i < 8; i++) {
                float4 a = As[ty * 8 + i][k4];
                acc[i].x = fmaf(a.x, b0.x, fmaf(a.y, b1.x, fmaf(a.z, b2.x, fmaf(a.w, b3.x, acc[i].x))));
                acc[i].y = fmaf(a.x, b0.y, fmaf(a.y, b1.y, fmaf(a.z, b2.y, fmaf(a.w, b3.y, acc[i].y))));
                acc[i].z = fmaf(a.x, b0.z, fmaf(a.y, b1.z, fmaf(a.z, b2.z, fmaf(a.w, b3.z, acc[i].z))));
                acc[i].w = fmaf(a.x, b0.w, fmaf(a.y, b1.w, fmaf(a.z, b2.w, fmaf(a.w, b3.w, acc[i].w))));
            }
        }
        __syncthreads();
    }

#pragma unroll
    for (int i = 0; i < 8; i++) {
        int row = row0 + ty * 8 + i;
        if (row < M) *(float4*)(C + (size_t)row * 128 + tx * 4) = acc[i];
    }
}

// ================= gather-aggregate (fused finalize, dual h output) =================
// wave per node. half = lane>>5 processes alternate neighbors; lane&31 owns 4 channels.
// 2 neighbor rows in flight per wave-instruction (float4/lane), shfl_xor(32) merge.
__global__ __launch_bounds__(THREADS) void k_gather_agg(const int* __restrict__ rowptr,
                                                        const int2* __restrict__ swPair,
                                                        const float* __restrict__ xw,
                                                        const float* __restrict__ dinv,
                                                        const float* __restrict__ bias,
                                                        float* __restrict__ h,
                                                        __bf16* __restrict__ h16, int n) {
    int node = blockIdx.x * 4 + (threadIdx.x >> 6);
    int lane = threadIdx.x & 63;
    int half = lane >> 5;
    int c = lane & 31;          // channels c*4 .. c*4+3
    if (node >= n) return;
    int beg = rowptr[node], end = rowptr[node + 1];
    float di = dinv[node];

    float ax = 0.f, ay = 0.f, az = 0.f, aw = 0.f;
    int j = beg;
    for (; j + 7 < end; j += 8) {
        int2 pw[4];
#pragma unroll
        for (int t = 0; t < 4; t++) pw[t] = swPair[j + 2 * t + half];
        float4 v[4];
#pragma unroll
        for (int t = 0; t < 4; t++)
            v[t] = *(const float4*)(xw + (size_t)pw[t].x * 128 + c * 4);
#pragma unroll
        for (int t = 0; t < 4; t++) {
            float wq = __int_as_float(pw[t].y);
            ax = fmaf(v[t].x, wq, ax);
            ay = fmaf(v[t].y, wq, ay);
            az = fmaf(v[t].z, wq, az);
            aw = fmaf(v[t].w, wq, aw);
        }
    }
    for (; j + 1 < end; j += 2) {
        int2 pw = swPair[j + half];
        float4 v = *(const float4*)(xw + (size_t)pw.x * 128 + c * 4);
        float wq = __int_as_float(pw.y);
        ax = fmaf(v.x, wq, ax);
        ay = fmaf(v.y, wq, ay);
        az = fmaf(v.z, wq, az);
        aw = fmaf(v.w, wq, aw);
    }
    if (j < end && half == 0) {
        int2 pw = swPair[j];
        float4 v = *(const float4*)(xw + (size_t)pw.x * 128 + c * 4);
        float wq = __int_as_float(pw.y);
        ax = fmaf(v.x, wq, ax);
        ay = fmaf(v.y, wq, ay);
        az = fmaf(v.z, wq, az);
        aw = fmaf(v.w, wq, aw);
    }

    // merge halves
    ax += __shfl_xor(ax, 32);
    ay += __shfl_xor(ay, 32);
    az += __shfl_xor(az, 32);
    aw += __shfl_xor(aw, 32);

    if (half == 0) {
        float4 xv = *(const float4*)(xw + (size_t)node * 128 + c * 4);
        float4 b = *(const float4*)(bias + c * 4);
        float dd = di * di;
        float rx = fmaxf(fmaf(ax, di, fmaf(xv.x, dd, b.x)), 0.f);
        float ry = fmaxf(fmaf(ay, di, fmaf(xv.y, dd, b.y)), 0.f);
        float rz = fmaxf(fmaf(az, di, fmaf(xv.z, dd, b.z)), 0.f);
        float rw = fmaxf(fmaf(aw, di, fmaf(xv.w, dd, b.w)), 0.f);
        *(float4*)(h + (size_t)node * 128 + c * 4) = make_float4(rx, ry, rz, rw);
        bf16x4 r16;
        r16[0] = (__bf16)rx; r16[1] = (__bf16)ry;
        r16[2] = (__bf16)rz; r16[3] = (__bf16)rw;
        *(bf16x4*)(h16 + (size_t)node * 128 + c * 4) = r16;
    }
}

// ================= B-pack: fc1w [256][128] f32 -> MFMA B-fragments bf16 =================
__global__ __launch_bounds__(THREADS) void k_pack_b(const float* __restrict__ fc1w,
                                                    __bf16* __restrict__ bpack) {
    int t = blockIdx.x * THREADS + threadIdx.x;   // 0..4095
    int lane = t & 63;
    int fi = t >> 6;          // ks*8+nt
    int nt = fi & 7, ks = fi >> 3;
    int krow = ks * 32 + (lane >> 4) * 8;
    int col = nt * 16 + (lane & 15);
    bf16x8 v;
#pragma unroll
    for (int i = 0; i < 8; i++) v[i] = (__bf16)fc1w[(size_t)(krow + i) * 128 + col];
    *(bf16x8*)(bpack + (size_t)t * 8) = v;
}

// ================= edge head (MFMA, dst-sorted; x from bf16, y from f32) =================
__global__ __launch_bounds__(THREADS) void k_edge_head_mfma(const int* __restrict__ srcSorted,
                                                            const int* __restrict__ dstSorted,
                                                            const int* __restrict__ edgePerm,
                                                            const float* __restrict__ h,
                                                            const __bf16* __restrict__ h16,
                                                            const __bf16* __restrict__ bpack,
                                                            const float* __restrict__ fc1b,
                                                            const float* __restrict__ fc2w,
                                                            const float* __restrict__ fc2b,
                                                            float* __restrict__ out, int E) {
    int tid = threadIdx.x;
    int w = tid >> 6;
    int lane = tid & 63;
    int m = lane & 15;        // A row (edge within wave)
    int kg = lane >> 4;       // k-group: feature = ks*32 + kg*8 + i
    int e0w = blockIdx.x * 64 + w * 16;
    int p = e0w + m;          // sorted position
    bool valid = p < E;
    int s = valid ? srcSorted[p] : 0;
    int d = valid ? dstSorted[p] : 0;
    const __bf16* px = h16 + (size_t)s * 128 + kg * 8;   // random -> bf16 (256B rows)
    const float*  py = h   + (size_t)d * 128 + kg * 8;   // sorted -> cache-hit f32

    // issue all loads first (ILP)
    bf16x8 xl[4];
    float4 y0l[4], y1l[4];
#pragma unroll
    for (int ks = 0; ks < 4; ks++) {
        xl[ks]  = *(const bf16x8*)(px + ks * 32);
        y0l[ks] = *(const float4*)(py + ks * 32);
        y1l[ks] = *(const float4*)(py + ks * 32 + 4);
    }

    bf16x8 afrag[8];
#pragma unroll
    for (int ks = 0; ks < 4; ks++) {
        float yf[8];
        yf[0] = y0l[ks].x; yf[1] = y0l[ks].y; yf[2] = y0l[ks].z; yf[3] = y0l[ks].w;
        yf[4] = y1l[ks].x; yf[5] = y1l[ks].y; yf[6] = y1l[ks].z; yf[7] = y1l[ks].w;
        bf16x8 pr, q;
#pragma unroll
        for (int i = 0; i < 8; i++) {
            float xf = (float)xl[ks][i];
            pr[i] = (__bf16)(xf * yf[i]);
            q[i]  = (__bf16)(xf - yf[i]);
        }
        afrag[ks] = pr;
        afrag[ks + 4] = q;
    }

    f32x4 acc[8];
#pragma unroll
    for (int i = 0; i < 8; i++) acc[i] = (f32x4){0.f, 0.f, 0.f, 0.f};

    const bf16x8* bfr = ((const bf16x8*)bpack) + lane;
#pragma unroll
    for (int ks = 0; ks < 8; ks++) {
#pragma unroll
        for (int nt = 0; nt < 8; nt++) {
            bf16x8 b = bfr[(size_t)(ks * 8 + nt) * 64];
            acc[nt] = __builtin_amdgcn_mfma_f32_16x16x32_bf16(afrag[ks], b, acc[nt], 0, 0, 0);
        }
    }

    // epilogue: lane holds cols n = nt*16 + (lane&15), rows m = (lane>>4)*4 + r
    int n0 = lane & 15;
    int rowg = lane >> 4;
    float partial[4] = {0.f, 0.f, 0.f, 0.f};
#pragma unroll
    for (int nt = 0; nt < 8; nt++) {
        float bb = fc1b[nt * 16 + n0];
        float ww = fc2w[nt * 16 + n0];
#pragma unroll
        for (int r = 0; r < 4; r++) {
            float z = fmaxf(acc[nt][r] + bb, 0.f);
            partial[r] = fmaf(z, ww, partial[r]);
        }
    }
#pragma unroll
    for (int r = 0; r < 4; r++) {
        partial[r] += __shfl_xor(partial[r], 1);
        partial[r] += __shfl_xor(partial[r], 2);
        partial[r] += __shfl_xor(partial[r], 4);
        partial[r] += __shfl_xor(partial[r], 8);
    }
    if (n0 == 0) {
        float b2 = fc2b[0];
#pragma unroll
        for (int r = 0; r < 4; r++) {
            int q = e0w + rowg * 4 + r;
            if (q < E) out[edgePerm[q]] = 1.0f / (1.0f + expf(-(partial[r] + b2)));
        }
    }
}

// ================= host =================
extern "C" void kernel_launch(void* const* d_in, const int* in_sizes, int n_in,
                              void* d_out, int out_size, void* d_ws, size_t ws_size,
                              hipStream_t stream) {
    const float* x    = (const float*)d_in[0];
    const int*   ei   = (const int*)d_in[1];
    const float* W1   = (const float*)d_in[2];
    const float* b1   = (const float*)d_in[3];
    const float* W2   = (const float*)d_in[4];
    const float* b2   = (const float*)d_in[5];
    const float* fc1w = (const float*)d_in[6];
    const float* fc1b = (const float*)d_in[7];
    const float* fc2w = (const float*)d_in[8];
    const float* fc2b = (const float*)d_in[9];

    int N = in_sizes[0] / 128;
    int E = in_sizes[1] / 2;
    const int* src = ei;
    const int* dst = ei + E;

    // ---- workspace layout ----
    char* ws = (char*)d_ws;
    size_t off = 0;
    auto alloc = [&](size_t bytes) { char* p = ws + off; off += (bytes + 255) & ~(size_t)255; return p; };
    int*    cnt       = (int*)   alloc((size_t)N * 4);
    int*    rowptr    = (int*)   alloc(((size_t)N + 1) * 4);
    int*    cursor    = (int*)   alloc((size_t)N * 4);
    int*    blockSums = (int*)   alloc(256 * 4);
    int*    srcSorted = (int*)   alloc((size_t)E * 4);
    int2*   swPair    = (int2*)  alloc((size_t)E * 8);
    int*    dstSorted = (int*)   alloc((size_t)E * 4);
    int*    edgePerm  = (int*)   alloc((size_t)E * 4);
    float*  dinv      = (float*) alloc((size_t)N * 4);
    __bf16* bpack     = (__bf16*)alloc((size_t)4096 * 8 * 2);     // 64 KB
    float*  xw        = (float*) alloc((size_t)N * 128 * 4);
    float*  h         = (float*) alloc((size_t)N * 128 * 4);
    __bf16* h16       = (__bf16*)alloc((size_t)N * 128 * 2);

    int gN     = (N + THREADS - 1) / THREADS;
    int gE     = (E + THREADS - 1) / THREADS;
    int nchunk = (N + 1023) / 1024;
    int gGemm  = (N + 63) / 64;
    int gGath  = (N + 3) / 4;
    int gHead  = (E + 63) / 64;

    // ---- CSR build + degrees + B-pack ----
    hipMemsetAsync(cnt, 0, (size_t)N * 4, stream);
    k_hist<<<gE, THREADS, 0, stream>>>(dst, cnt, E);
    k_dinv<<<gN, THREADS, 0, stream>>>(cnt, dinv, N);
    k_scan1<<<nchunk, THREADS, 0, stream>>>(cnt, rowptr, blockSums, N);
    k_scan2<<<1, THREADS, 0, stream>>>(blockSums, rowptr, nchunk, N, E);
    k_scan3<<<gN, THREADS, 0, stream>>>(rowptr, blockSums, N);
    hipMemsetAsync(cursor, 0, (size_t)N * 4, stream);
    k_scatter<<<gE, THREADS, 0, stream>>>(src, dst, rowptr, dinv, cursor,
                                          srcSorted, swPair, dstSorted, edgePerm, E);
    k_pack_b<<<16, THREADS, 0, stream>>>(fc1w, bpack);

    // ---- layer 1 ----
    k_gemm128<<<gGemm, THREADS, 0, stream>>>(x, W1, xw, N);
    k_gather_agg<<<gGath, THREADS, 0, stream>>>(rowptr, swPair, xw, dinv, b1, h, h16, N);

    // ---- layer 2 ----
    k_gemm128<<<gGemm, THREADS, 0, stream>>>(h, W2, xw, N);
    k_gather_agg<<<gGath, THREADS, 0, stream>>>(rowptr, swPair, xw, dinv, b2, h, h16, N);

    // ---- edge head (MFMA, sorted order) ----
    k_edge_head_mfma<<<gHead, THREADS, 0, stream>>>(srcSorted, dstSorted, edgePerm,
                                                    h, h16, bpack, fc1b, fc2w, fc2b,
                                                    (float*)d_out, E);
}

// Round 6
// 712.963 us; speedup vs baseline: 10.3964x; 1.1165x over previous
//
#include <hip/hip_runtime.h>

#define THREADS 256

typedef __bf16 bf16x8 __attribute__((ext_vector_type(8)));
typedef __bf16 bf16x4 __attribute__((ext_vector_type(4)));
typedef float  f32x4  __attribute__((ext_vector_type(4)));

// ================= CSR build: histogram -> scan -> scatter =================

__global__ __launch_bounds__(THREADS) void k_hist(const int* __restrict__ dst,
                                                  int* __restrict__ cnt, int E) {
    int e = blockIdx.x * THREADS + threadIdx.x;
    if (e < E) atomicAdd(&cnt[dst[e]], 1);
}

__global__ __launch_bounds__(THREADS) void k_dinv(const int* __restrict__ cnt,
                                                  float* __restrict__ dinv, int n) {
    int i = blockIdx.x * THREADS + threadIdx.x;
    if (i < n) dinv[i] = rsqrtf((float)cnt[i] + 1.0f);
}

__global__ __launch_bounds__(THREADS) void k_scan1(const int* __restrict__ cnt,
                                                   int* __restrict__ rowptr,
                                                   int* __restrict__ blockSums, int n) {
    __shared__ int part[THREADS];
    int tid = threadIdx.x;
    int base = blockIdx.x * 1024 + tid * 4;
    int v0 = (base + 0 < n) ? cnt[base + 0] : 0;
    int v1 = (base + 1 < n) ? cnt[base + 1] : 0;
    int v2 = (base + 2 < n) ? cnt[base + 2] : 0;
    int v3 = (base + 3 < n) ? cnt[base + 3] : 0;
    part[tid] = v0 + v1 + v2 + v3;
    __syncthreads();
    for (int off = 1; off < THREADS; off <<= 1) {
        int t = 0;
        if (tid >= off) t = part[tid - off];
        __syncthreads();
        if (tid >= off) part[tid] += t;
        __syncthreads();
    }
    int excl = (tid == 0) ? 0 : part[tid - 1];
    if (tid == THREADS - 1) blockSums[blockIdx.x] = part[THREADS - 1];
    int run = excl;
    if (base + 0 < n) rowptr[base + 0] = run; run += v0;
    if (base + 1 < n) rowptr[base + 1] = run; run += v1;
    if (base + 2 < n) rowptr[base + 2] = run; run += v2;
    if (base + 3 < n) rowptr[base + 3] = run;
}

__global__ __launch_bounds__(THREADS) void k_scan2(int* __restrict__ blockSums,
                                                   int* __restrict__ rowptr,
                                                   int nchunks, int n, int E) {
    __shared__ int part[THREADS];
    int tid = threadIdx.x;
    int v = (tid < nchunks) ? blockSums[tid] : 0;
    part[tid] = v;
    __syncthreads();
    for (int off = 1; off < THREADS; off <<= 1) {
        int t = 0;
        if (tid >= off) t = part[tid - off];
        __syncthreads();
        if (tid >= off) part[tid] += t;
        __syncthreads();
    }
    int excl = (tid == 0) ? 0 : part[tid - 1];
    if (tid < nchunks) blockSums[tid] = excl;
    if (tid == 0) rowptr[n] = E;
}

__global__ __launch_bounds__(THREADS) void k_scan3(int* __restrict__ rowptr,
                                                   const int* __restrict__ blockSums, int n) {
    int i = blockIdx.x * THREADS + threadIdx.x;
    if (i < n) rowptr[i] += blockSums[i >> 10];
}

// writes: srcSorted (src id), swPair {src, dinv[src]}, dstSorted, edgePerm
__global__ __launch_bounds__(THREADS) void k_scatter(const int* __restrict__ src,
                                                     const int* __restrict__ dst,
                                                     const int* __restrict__ rowptr,
                                                     const float* __restrict__ dinv,
                                                     int* __restrict__ cursor,
                                                     int* __restrict__ srcSorted,
                                                     int2* __restrict__ swPair,
                                                     int* __restrict__ dstSorted,
                                                     int* __restrict__ edgePerm, int E) {
    int e = blockIdx.x * THREADS + threadIdx.x;
    if (e >= E) return;
    int d = dst[e];
    int s = src[e];
    int pos = rowptr[d] + atomicAdd(&cursor[d], 1);
    srcSorted[pos] = s;
    swPair[pos] = make_int2(s, __float_as_int(dinv[s]));
    dstSorted[pos] = d;
    edgePerm[pos] = e;
}

// ================= GEMM: C[M][128] = A[M][128] @ B[128][128]; also bf16 copy ====
__global__ __launch_bounds__(THREADS) void k_gemm128(const float* __restrict__ A,
                                                     const float* __restrict__ B,
                                                     float* __restrict__ C,
                                                     __bf16* __restrict__ C16, int M) {
    __shared__ float4 As[64][8];
    __shared__ float4 Bs[32][32];

    int tid = threadIdx.x;
    int tx = tid & 31;
    int ty = tid >> 5;
    int row0 = blockIdx.x * 64;

    float4 acc[8];
#pragma unroll
    for (int i = 0; i < 8; i++) acc[i] = make_float4(0.f, 0.f, 0.f, 0.f);

    for (int k0 = 0; k0 < 128; k0 += 32) {
#pragma unroll
        for (int i = 0; i < 2; i++) {
            int idx = tid + i * 256;
            int r = idx >> 3, q = idx & 7;
            int row = row0 + r;
            float4 v = make_float4(0.f, 0.f, 0.f, 0.f);
            if (row < M) v = *(const float4*)(A + (size_t)row * 128 + k0 + q * 4);
            As[r][q] = v;
        }
#pragma unroll
        for (int i = 0; i < 4; i++) {
            int idx = tid + i * 256;
            int r = idx >> 5, c4 = idx & 31;
            Bs[r][c4] = *(const float4*)(B + (size_t)(k0 + r) * 128 + c4 * 4);
        }
        __syncthreads();

#pragma unroll
        for (int k4 = 0; k4 < 8; k4++) {
            float4 b0 = Bs[k4 * 4 + 0][tx];
            float4 b1 = Bs[k4 * 4 + 1][tx];
            float4 b2 = Bs[k4 * 4 + 2][tx];
            float4 b3 = Bs[k4 * 4 + 3][tx];
#pragma unroll
            for (int i = 0; i < 8; i++) {
                float4 a = As[ty * 8 + i][k4];
                acc[i].x = fmaf(a.x, b0.x, fmaf(a.y, b1.x, fmaf(a.z, b2.x, fmaf(a.w, b3.x, acc[i].x))));
                acc[i].y = fmaf(a.x, b0.y, fmaf(a.y, b1.y, fmaf(a.z, b2.y, fmaf(a.w, b3.y, acc[i].y))));
                acc[i].z = fmaf(a.x, b0.z, fmaf(a.y, b1.z, fmaf(a.z, b2.z, fmaf(a.w, b3.z, acc[i].z))));
                acc[i].w = fmaf(a.x, b0.w, fmaf(a.y, b1.w, fmaf(a.z, b2.w, fmaf(a.w, b3.w, acc[i].w))));
            }
        }
        __syncthreads();
    }

#pragma unroll
    for (int i = 0; i < 8; i++) {
        int row = row0 + ty * 8 + i;
        if (row < M) {
            *(float4*)(C + (size_t)row * 128 + tx * 4) = acc[i];
            bf16x4 c16;
            c16[0] = (__bf16)acc[i].x; c16[1] = (__bf16)acc[i].y;
            c16[2] = (__bf16)acc[i].z; c16[3] = (__bf16)acc[i].w;
            *(bf16x4*)(C16 + (size_t)row * 128 + tx * 4) = c16;
        }
    }
}

// ================= gather-aggregate (bf16 gather, fused finalize, dual h out) ====
// wave per node. quarter q = lane>>4 handles neighbor j+q; c = lane&15 owns
// channels c*8..c*8+7 (bf16x8 = 16B load). 4 rows in flight per wave-instr,
// 8 rows with 2-deep unroll. f32 accumulate; shfl_xor(16),(32) merge.
__global__ __launch_bounds__(THREADS) void k_gather_agg(const int* __restrict__ rowptr,
                                                        const int2* __restrict__ swPair,
                                                        const __bf16* __restrict__ xw16,
                                                        const float* __restrict__ xw,
                                                        const float* __restrict__ dinv,
                                                        const float* __restrict__ bias,
                                                        float* __restrict__ h,
                                                        __bf16* __restrict__ h16, int n) {
    int node = blockIdx.x * 4 + (threadIdx.x >> 6);
    int lane = threadIdx.x & 63;
    int q = lane >> 4;
    int c = lane & 15;          // channels c*8 .. c*8+7
    if (node >= n) return;
    int beg = rowptr[node], end = rowptr[node + 1];
    float di = dinv[node];

    float acc[8];
#pragma unroll
    for (int i = 0; i < 8; i++) acc[i] = 0.f;

    int j = beg;
    for (; j + 7 < end; j += 8) {
        int2 pw0 = swPair[j + q];
        int2 pw1 = swPair[j + 4 + q];
        bf16x8 v0 = *(const bf16x8*)(xw16 + (size_t)pw0.x * 128 + c * 8);
        bf16x8 v1 = *(const bf16x8*)(xw16 + (size_t)pw1.x * 128 + c * 8);
        float w0 = __int_as_float(pw0.y);
        float w1 = __int_as_float(pw1.y);
#pragma unroll
        for (int i = 0; i < 8; i++) {
            acc[i] = fmaf((float)v0[i], w0, acc[i]);
            acc[i] = fmaf((float)v1[i], w1, acc[i]);
        }
    }
    for (; j + 3 < end; j += 4) {
        int2 pw = swPair[j + q];
        bf16x8 v = *(const bf16x8*)(xw16 + (size_t)pw.x * 128 + c * 8);
        float w = __int_as_float(pw.y);
#pragma unroll
        for (int i = 0; i < 8; i++) acc[i] = fmaf((float)v[i], w, acc[i]);
    }
    int rem = end - j;
    if (q < rem) {
        int2 pw = swPair[j + q];
        bf16x8 v = *(const bf16x8*)(xw16 + (size_t)pw.x * 128 + c * 8);
        float w = __int_as_float(pw.y);
#pragma unroll
        for (int i = 0; i < 8; i++) acc[i] = fmaf((float)v[i], w, acc[i]);
    }

    // merge quarters
#pragma unroll
    for (int i = 0; i < 8; i++) {
        acc[i] += __shfl_xor(acc[i], 16);
        acc[i] += __shfl_xor(acc[i], 32);
    }

    if (q == 0) {
        float4 xv0 = *(const float4*)(xw + (size_t)node * 128 + c * 8);
        float4 xv1 = *(const float4*)(xw + (size_t)node * 128 + c * 8 + 4);
        float4 b0 = *(const float4*)(bias + c * 8);
        float4 b1 = *(const float4*)(bias + c * 8 + 4);
        float dd = di * di;
        float r[8];
        r[0] = fmaxf(fmaf(acc[0], di, fmaf(xv0.x, dd, b0.x)), 0.f);
        r[1] = fmaxf(fmaf(acc[1], di, fmaf(xv0.y, dd, b0.y)), 0.f);
        r[2] = fmaxf(fmaf(acc[2], di, fmaf(xv0.z, dd, b0.z)), 0.f);
        r[3] = fmaxf(fmaf(acc[3], di, fmaf(xv0.w, dd, b0.w)), 0.f);
        r[4] = fmaxf(fmaf(acc[4], di, fmaf(xv1.x, dd, b1.x)), 0.f);
        r[5] = fmaxf(fmaf(acc[5], di, fmaf(xv1.y, dd, b1.y)), 0.f);
        r[6] = fmaxf(fmaf(acc[6], di, fmaf(xv1.z, dd, b1.z)), 0.f);
        r[7] = fmaxf(fmaf(acc[7], di, fmaf(xv1.w, dd, b1.w)), 0.f);
        *(float4*)(h + (size_t)node * 128 + c * 8)     = make_float4(r[0], r[1], r[2], r[3]);
        *(float4*)(h + (size_t)node * 128 + c * 8 + 4) = make_float4(r[4], r[5], r[6], r[7]);
        bf16x8 r16;
#pragma unroll
        for (int i = 0; i < 8; i++) r16[i] = (__bf16)r[i];
        *(bf16x8*)(h16 + (size_t)node * 128 + c * 8) = r16;
    }
}

// ================= B-pack: fc1w [256][128] f32 -> MFMA B-fragments bf16 =================
__global__ __launch_bounds__(THREADS) void k_pack_b(const float* __restrict__ fc1w,
                                                    __bf16* __restrict__ bpack) {
    int t = blockIdx.x * THREADS + threadIdx.x;   // 0..4095
    int lane = t & 63;
    int fi = t >> 6;          // ks*8+nt
    int nt = fi & 7, ks = fi >> 3;
    int krow = ks * 32 + (lane >> 4) * 8;
    int col = nt * 16 + (lane & 15);
    bf16x8 v;
#pragma unroll
    for (int i = 0; i < 8; i++) v[i] = (__bf16)fc1w[(size_t)(krow + i) * 128 + col];
    *(bf16x8*)(bpack + (size_t)t * 8) = v;
}

// ================= edge head (MFMA, dst-sorted; x and y from bf16 h16) =========
__global__ __launch_bounds__(THREADS) void k_edge_head_mfma(const int* __restrict__ srcSorted,
                                                            const int* __restrict__ dstSorted,
                                                            const int* __restrict__ edgePerm,
                                                            const __bf16* __restrict__ h16,
                                                            const __bf16* __restrict__ bpack,
                                                            const float* __restrict__ fc1b,
                                                            const float* __restrict__ fc2w,
                                                            const float* __restrict__ fc2b,
                                                            float* __restrict__ out, int E) {
    int tid = threadIdx.x;
    int w = tid >> 6;
    int lane = tid & 63;
    int m = lane & 15;        // A row (edge within wave)
    int kg = lane >> 4;       // k-group: feature = ks*32 + kg*8 + i
    int e0w = blockIdx.x * 64 + w * 16;
    int p = e0w + m;          // sorted position
    bool valid = p < E;
    int s = valid ? srcSorted[p] : 0;
    int d = valid ? dstSorted[p] : 0;
    const __bf16* px = h16 + (size_t)s * 128 + kg * 8;   // random (256B rows)
    const __bf16* py = h16 + (size_t)d * 128 + kg * 8;   // sorted -> cache-hit

    // issue all loads first (ILP)
    bf16x8 xl[4], yl[4];
#pragma unroll
    for (int ks = 0; ks < 4; ks++) {
        xl[ks] = *(const bf16x8*)(px + ks * 32);
        yl[ks] = *(const bf16x8*)(py + ks * 32);
    }

    bf16x8 afrag[8];
#pragma unroll
    for (int ks = 0; ks < 4; ks++) {
        bf16x8 pr, qd;
#pragma unroll
        for (int i = 0; i < 8; i++) {
            float xf = (float)xl[ks][i];
            float yf = (float)yl[ks][i];
            pr[i] = (__bf16)(xf * yf);
            qd[i] = (__bf16)(xf - yf);
        }
        afrag[ks] = pr;
        afrag[ks + 4] = qd;
    }

    f32x4 acc[8];
#pragma unroll
    for (int i = 0; i < 8; i++) acc[i] = (f32x4){0.f, 0.f, 0.f, 0.f};

    const bf16x8* bfr = ((const bf16x8*)bpack) + lane;
#pragma unroll
    for (int ks = 0; ks < 8; ks++) {
#pragma unroll
        for (int nt = 0; nt < 8; nt++) {
            bf16x8 b = bfr[(size_t)(ks * 8 + nt) * 64];
            acc[nt] = __builtin_amdgcn_mfma_f32_16x16x32_bf16(afrag[ks], b, acc[nt], 0, 0, 0);
        }
    }

    // epilogue: lane holds cols n = nt*16 + (lane&15), rows m = (lane>>4)*4 + r
    int n0 = lane & 15;
    int rowg = lane >> 4;
    float partial[4] = {0.f, 0.f, 0.f, 0.f};
#pragma unroll
    for (int nt = 0; nt < 8; nt++) {
        float bb = fc1b[nt * 16 + n0];
        float ww = fc2w[nt * 16 + n0];
#pragma unroll
        for (int r = 0; r < 4; r++) {
            float z = fmaxf(acc[nt][r] + bb, 0.f);
            partial[r] = fmaf(z, ww, partial[r]);
        }
    }
#pragma unroll
    for (int r = 0; r < 4; r++) {
        partial[r] += __shfl_xor(partial[r], 1);
        partial[r] += __shfl_xor(partial[r], 2);
        partial[r] += __shfl_xor(partial[r], 4);
        partial[r] += __shfl_xor(partial[r], 8);
    }
    if (n0 == 0) {
        float b2 = fc2b[0];
#pragma unroll
        for (int r = 0; r < 4; r++) {
            int qq = e0w + rowg * 4 + r;
            if (qq < E) out[edgePerm[qq]] = 1.0f / (1.0f + expf(-(partial[r] + b2)));
        }
    }
}

// ================= host =================
extern "C" void kernel_launch(void* const* d_in, const int* in_sizes, int n_in,
                              void* d_out, int out_size, void* d_ws, size_t ws_size,
                              hipStream_t stream) {
    const float* x    = (const float*)d_in[0];
    const int*   ei   = (const int*)d_in[1];
    const float* W1   = (const float*)d_in[2];
    const float* b1   = (const float*)d_in[3];
    const float* W2   = (const float*)d_in[4];
    const float* b2   = (const float*)d_in[5];
    const float* fc1w = (const float*)d_in[6];
    const float* fc1b = (const float*)d_in[7];
    const float* fc2w = (const float*)d_in[8];
    const float* fc2b = (const float*)d_in[9];

    int N = in_sizes[0] / 128;
    int E = in_sizes[1] / 2;
    const int* src = ei;
    const int* dst = ei + E;

    // ---- workspace layout ----
    char* ws = (char*)d_ws;
    size_t off = 0;
    auto alloc = [&](size_t bytes) { char* p = ws + off; off += (bytes + 255) & ~(size_t)255; return p; };
    int*    cnt       = (int*)   alloc((size_t)N * 4);
    int*    rowptr    = (int*)   alloc(((size_t)N + 1) * 4);
    int*    cursor    = (int*)   alloc((size_t)N * 4);
    int*    blockSums = (int*)   alloc(256 * 4);
    int*    srcSorted = (int*)   alloc((size_t)E * 4);
    int2*   swPair    = (int2*)  alloc((size_t)E * 8);
    int*    dstSorted = (int*)   alloc((size_t)E * 4);
    int*    edgePerm  = (int*)   alloc((size_t)E * 4);
    float*  dinv      = (float*) alloc((size_t)N * 4);
    __bf16* bpack     = (__bf16*)alloc((size_t)4096 * 8 * 2);     // 64 KB
    float*  xw        = (float*) alloc((size_t)N * 128 * 4);
    __bf16* xw16      = (__bf16*)alloc((size_t)N * 128 * 2);
    float*  h         = (float*) alloc((size_t)N * 128 * 4);
    __bf16* h16       = (__bf16*)alloc((size_t)N * 128 * 2);

    int gN     = (N + THREADS - 1) / THREADS;
    int gE     = (E + THREADS - 1) / THREADS;
    int nchunk = (N + 1023) / 1024;
    int gGemm  = (N + 63) / 64;
    int gGath  = (N + 3) / 4;
    int gHead  = (E + 63) / 64;

    // ---- CSR build + degrees + B-pack ----
    hipMemsetAsync(cnt, 0, (size_t)N * 4, stream);
    k_hist<<<gE, THREADS, 0, stream>>>(dst, cnt, E);
    k_dinv<<<gN, THREADS, 0, stream>>>(cnt, dinv, N);
    k_scan1<<<nchunk, THREADS, 0, stream>>>(cnt, rowptr, blockSums, N);
    k_scan2<<<1, THREADS, 0, stream>>>(blockSums, rowptr, nchunk, N, E);
    k_scan3<<<gN, THREADS, 0, stream>>>(rowptr, blockSums, N);
    hipMemsetAsync(cursor, 0, (size_t)N * 4, stream);
    k_scatter<<<gE, THREADS, 0, stream>>>(src, dst, rowptr, dinv, cursor,
                                          srcSorted, swPair, dstSorted, edgePerm, E);
    k_pack_b<<<16, THREADS, 0, stream>>>(fc1w, bpack);

    // ---- layer 1 ----
    k_gemm128<<<gGemm, THREADS, 0, stream>>>(x, W1, xw, xw16, N);
    k_gather_agg<<<gGath, THREADS, 0, stream>>>(rowptr, swPair, xw16, xw, dinv, b1, h, h16, N);

    // ---- layer 2 ----
    k_gemm128<<<gGemm, THREADS, 0, stream>>>(h, W2, xw, xw16, N);
    k_gather_agg<<<gGath, THREADS, 0, stream>>>(rowptr, swPair, xw16, xw, dinv, b2, h, h16, N);

    // ---- edge head (MFMA, sorted order) ----
    k_edge_head_mfma<<<gHead, THREADS, 0, stream>>>(srcSorted, dstSorted, edgePerm,
                                                    h16, bpack, fc1b, fc2w, fc2b,
                                                    (float*)d_out, E);
}